// Round 1
// baseline (1830.077 us; speedup 1.0000x reference)
//
#include <hip/hip_runtime.h>
#include <hip/hip_bf16.h>

// Problem constants
#define Bc 2
#define Sc 4096
#define Ec 768
#define Hc 12
#define HDc 64
#define Wc 256
#define Gc 32
#define Mtot (Bc*Sc)   // 8192

// ---------------------------------------------------------------------------
// Kernel 1: fused projection GEMMs.  C_z = hs @ W_z + b_z (q scaled by 0.125)
// grid (64, 6, 5), block 256.  128x128 tile, BK=16, 8x8 per thread.
// ---------------------------------------------------------------------------
__global__ __launch_bounds__(256) void proj_gemm(
    const float* __restrict__ A,
    const float* __restrict__ Wq,  const float* __restrict__ bq,  float* __restrict__ Cq,
    const float* __restrict__ Wk,  const float* __restrict__ bk,  float* __restrict__ Ck,
    const float* __restrict__ Wv,  const float* __restrict__ bv,  float* __restrict__ Cv,
    const float* __restrict__ Wkg, const float* __restrict__ bkg, float* __restrict__ Ckg,
    const float* __restrict__ Wvg, const float* __restrict__ bvg, float* __restrict__ Cvg)
{
    const int z = blockIdx.z;
    const float* Wm; const float* bias; float* C; float scale = 1.0f;
    switch (z) {
        case 0:  Wm = Wq;  bias = bq;  C = Cq; scale = 0.125f; break;
        case 1:  Wm = Wk;  bias = bk;  C = Ck;  break;
        case 2:  Wm = Wv;  bias = bv;  C = Cv;  break;
        case 3:  Wm = Wkg; bias = bkg; C = Ckg; break;
        default: Wm = Wvg; bias = bvg; C = Cvg; break;
    }

    __shared__ float As[16][132];   // [k][m], padded
    __shared__ float Bs[16][132];   // [k][n], padded

    const int tid = threadIdx.x;
    const int m0 = blockIdx.x * 128;
    const int n0 = blockIdx.y * 128;
    const int tm = (tid >> 4) * 8;   // 0..120
    const int tn = (tid & 15) * 8;   // 0..120

    float acc[8][8];
    #pragma unroll
    for (int i = 0; i < 8; ++i)
        #pragma unroll
        for (int j = 0; j < 8; ++j) acc[i][j] = 0.f;

    for (int k0 = 0; k0 < Ec; k0 += 16) {
        // A tile: 128 rows x 16 cols = 512 float4
        #pragma unroll
        for (int l = 0; l < 2; ++l) {
            int id  = tid + l * 256;
            int row = id >> 2;          // 0..127
            int c4  = (id & 3) * 4;     // 0,4,8,12
            float4 av = *reinterpret_cast<const float4*>(&A[(size_t)(m0 + row) * Ec + k0 + c4]);
            As[c4 + 0][row] = av.x;
            As[c4 + 1][row] = av.y;
            As[c4 + 2][row] = av.z;
            As[c4 + 3][row] = av.w;
        }
        // B tile: 16 rows x 128 cols = 512 float4
        #pragma unroll
        for (int l = 0; l < 2; ++l) {
            int id  = tid + l * 256;
            int row = id >> 5;          // 0..15
            int c4  = (id & 31) * 4;    // 0..124
            *reinterpret_cast<float4*>(&Bs[row][c4]) =
                *reinterpret_cast<const float4*>(&Wm[(size_t)(k0 + row) * Ec + n0 + c4]);
        }
        __syncthreads();
        #pragma unroll
        for (int kk = 0; kk < 16; ++kk) {
            float a[8], b[8];
            #pragma unroll
            for (int i = 0; i < 8; ++i) a[i] = As[kk][tm + i];
            #pragma unroll
            for (int j = 0; j < 8; ++j) b[j] = Bs[kk][tn + j];
            #pragma unroll
            for (int i = 0; i < 8; ++i)
                #pragma unroll
                for (int j = 0; j < 8; ++j)
                    acc[i][j] = fmaf(a[i], b[j], acc[i][j]);
        }
        __syncthreads();
    }

    #pragma unroll
    for (int i = 0; i < 8; ++i) {
        float r[8];
        #pragma unroll
        for (int j = 0; j < 8; ++j)
            r[j] = (acc[i][j] + bias[n0 + tn + j]) * scale;
        float4 o0 = { r[0], r[1], r[2], r[3] };
        float4 o1 = { r[4], r[5], r[6], r[7] };
        float* cp = &C[(size_t)(m0 + tm + i) * Ec + n0 + tn];
        *reinterpret_cast<float4*>(cp)     = o0;
        *reinterpret_cast<float4*>(cp + 4) = o1;
    }
}

// ---------------------------------------------------------------------------
// Kernel 1b: qg = (hs[:, :G] @ Wqg + bqg) * 0.125  -- tiny (64 x 768)
// grid 192, block 256, one output element per thread.
// ---------------------------------------------------------------------------
__global__ void qg_kernel(const float* __restrict__ hs, const float* __restrict__ Wqg,
                          const float* __restrict__ bqg, float* __restrict__ qg)
{
    int idx = blockIdx.x * 256 + threadIdx.x;   // 0 .. 64*768-1
    int r = idx / Ec, n = idx - r * Ec;
    int b = r >> 5, g = r & 31;
    const float* a = &hs[(size_t)(b * Sc + g) * Ec];
    float s = 0.f;
    for (int k2 = 0; k2 < Ec; ++k2)
        s = fmaf(a[k2], Wqg[(size_t)k2 * Ec + n], s);
    qg[idx] = (s + bqg[n]) * 0.125f;
}

// ---------------------------------------------------------------------------
// Kernel 2: banded sliding-window attention + 32 global-key scores.
// grid (S/64, H, B), block 64 (1 wave).  Lane = query.  Online softmax.
// ---------------------------------------------------------------------------
__global__ __launch_bounds__(64, 2) void band_attn(
    const float* __restrict__ q, const float* __restrict__ k, const float* __restrict__ v,
    const float* __restrict__ mask, float* __restrict__ out)
{
    const int t  = threadIdx.x;          // query slot 0..63
    const int i0 = blockIdx.x * 64;
    const int h  = blockIdx.y;
    const int b  = blockIdx.z;
    const int i  = i0 + t;               // absolute query index

    __shared__ float ks[64][64];
    __shared__ float vs[64][64];
    __shared__ float fm[64];

    const size_t base = ((size_t)b * Sc) * Ec + (size_t)h * HDc;

    float qr[64];
    {
        const float* qp = &q[base + (size_t)i * Ec];
        #pragma unroll
        for (int c = 0; c < 16; ++c) {
            float4 t4 = *reinterpret_cast<const float4*>(&qp[c * 4]);
            qr[c*4+0] = t4.x; qr[c*4+1] = t4.y; qr[c*4+2] = t4.z; qr[c*4+3] = t4.w;
        }
    }

    float m = -3.0e38f, l = 0.f;
    float o[64];
    #pragma unroll
    for (int d = 0; d < 64; ++d) o[d] = 0.f;

    // tile 0: global keys [0,32); tiles 1..9: window [i0-256 + (tt-1)*64, +64)
    for (int tt = 0; tt < 10; ++tt) {
        const bool is_g = (tt == 0);
        const int  j0   = is_g ? 0  : (i0 - Wc + (tt - 1) * 64);
        const int  rows = is_g ? Gc : 64;

        __syncthreads();
        // stage K/V tile (float4 per thread-iteration)
        #pragma unroll
        for (int r4 = 0; r4 < 16; ++r4) {
            int id  = r4 * 64 + t;
            int row = id >> 4;          // 0..63
            int c4  = (id & 15) * 4;    // 0..60
            int j   = j0 + row;
            if (row < rows && j >= 0 && j < Sc) {
                *reinterpret_cast<float4*>(&ks[row][c4]) =
                    *reinterpret_cast<const float4*>(&k[base + (size_t)j * Ec + c4]);
                *reinterpret_cast<float4*>(&vs[row][c4]) =
                    *reinterpret_cast<const float4*>(&v[base + (size_t)j * Ec + c4]);
            }
        }
        if (t < rows) {
            int j = j0 + t;
            float mv = (j >= 0 && j < Sc) ? mask[b * Sc + j] : 0.f;
            fm[t] = (!is_g && mv != 0.f) ? -10000.f : 0.f;
        }
        __syncthreads();

        for (int jj = 0; jj < rows; ++jj) {
            int j = j0 + jj;
            bool valid = is_g || (j >= 0 && j < Sc && j >= i - Wc && j <= i + Wc);
            if (valid) {
                // s = q . k_j + fm
                const float4* kp4 = reinterpret_cast<const float4*>(&ks[jj][0]);
                float4 a4 = {0.f, 0.f, 0.f, 0.f};
                #pragma unroll
                for (int c = 0; c < 16; ++c) {
                    float4 kv = kp4[c];
                    a4.x = fmaf(qr[c*4+0], kv.x, a4.x);
                    a4.y = fmaf(qr[c*4+1], kv.y, a4.y);
                    a4.z = fmaf(qr[c*4+2], kv.z, a4.z);
                    a4.w = fmaf(qr[c*4+3], kv.w, a4.w);
                }
                float s = fm[jj] + ((a4.x + a4.y) + (a4.z + a4.w));
                const float4* vp4 = reinterpret_cast<const float4*>(&vs[jj][0]);
                if (s <= m) {
                    float p = __expf(s - m);
                    l += p;
                    #pragma unroll
                    for (int c = 0; c < 16; ++c) {
                        float4 vv = vp4[c];
                        o[c*4+0] = fmaf(p, vv.x, o[c*4+0]);
                        o[c*4+1] = fmaf(p, vv.y, o[c*4+1]);
                        o[c*4+2] = fmaf(p, vv.z, o[c*4+2]);
                        o[c*4+3] = fmaf(p, vv.w, o[c*4+3]);
                    }
                } else {
                    float cc = __expf(m - s);
                    l = fmaf(l, cc, 1.0f);
                    #pragma unroll
                    for (int c = 0; c < 16; ++c) {
                        float4 vv = vp4[c];
                        o[c*4+0] = fmaf(o[c*4+0], cc, vv.x);
                        o[c*4+1] = fmaf(o[c*4+1], cc, vv.y);
                        o[c*4+2] = fmaf(o[c*4+2], cc, vv.z);
                        o[c*4+3] = fmaf(o[c*4+3], cc, vv.w);
                    }
                    m = s;
                }
            }
        }
    }

    float rinv = 1.0f / l;
    float* op = const_cast<float*>(&out[base + (size_t)i * Ec]);
    #pragma unroll
    for (int c = 0; c < 16; ++c) {
        float4 t4 = { o[c*4+0]*rinv, o[c*4+1]*rinv, o[c*4+2]*rinv, o[c*4+3]*rinv };
        *reinterpret_cast<float4*>(&op[c * 4]) = t4;
    }
}

// ---------------------------------------------------------------------------
// Kernel 3: global-row attention, partial over key chunks of 512.
// grid (8, H, B), block 64.  Lane = query(0..31) + 32*half; halves split keys.
// ---------------------------------------------------------------------------
__global__ __launch_bounds__(64, 2) void global_partial(
    const float* __restrict__ qg, const float* __restrict__ kg, const float* __restrict__ vg,
    const float* __restrict__ mask,
    float* __restrict__ pm, float* __restrict__ pl, float* __restrict__ po)
{
    const int t     = threadIdx.x;
    const int qidx  = t & 31;
    const int half  = t >> 5;
    const int chunk = blockIdx.x;   // 0..7
    const int h     = blockIdx.y;
    const int b     = blockIdx.z;

    __shared__ float ks[64][64];
    __shared__ float vs[64][64];
    __shared__ float fl[64];        // masked flag

    const size_t kbase = ((size_t)b * Sc) * Ec + (size_t)h * HDc;

    float qr[64];
    {
        const float* qp = &qg[(size_t)(b * Gc + qidx) * Ec + h * HDc];
        #pragma unroll
        for (int c = 0; c < 16; ++c) {
            float4 t4 = *reinterpret_cast<const float4*>(&qp[c * 4]);
            qr[c*4+0] = t4.x; qr[c*4+1] = t4.y; qr[c*4+2] = t4.z; qr[c*4+3] = t4.w;
        }
    }

    float m = -3.0e38f, l = 0.f;
    float o[64];
    #pragma unroll
    for (int d = 0; d < 64; ++d) o[d] = 0.f;

    const int c0 = chunk * 512;
    for (int tt = 0; tt < 8; ++tt) {
        const int j0 = c0 + tt * 64;
        __syncthreads();
        #pragma unroll
        for (int r4 = 0; r4 < 16; ++r4) {
            int id  = r4 * 64 + t;
            int row = id >> 4;
            int c4  = (id & 15) * 4;
            int j   = j0 + row;
            *reinterpret_cast<float4*>(&ks[row][c4]) =
                *reinterpret_cast<const float4*>(&kg[kbase + (size_t)j * Ec + c4]);
            *reinterpret_cast<float4*>(&vs[row][c4]) =
                *reinterpret_cast<const float4*>(&vg[kbase + (size_t)j * Ec + c4]);
        }
        {
            int j = j0 + t;
            fl[t] = (mask[b * Sc + j] < 0.f) ? 1.f : 0.f;
        }
        __syncthreads();

        for (int jj2 = 0; jj2 < 32; ++jj2) {
            int jj = half + 2 * jj2;
            const float4* kp4 = reinterpret_cast<const float4*>(&ks[jj][0]);
            float4 a4 = {0.f, 0.f, 0.f, 0.f};
            #pragma unroll
            for (int c = 0; c < 16; ++c) {
                float4 kv = kp4[c];
                a4.x = fmaf(qr[c*4+0], kv.x, a4.x);
                a4.y = fmaf(qr[c*4+1], kv.y, a4.y);
                a4.z = fmaf(qr[c*4+2], kv.z, a4.z);
                a4.w = fmaf(qr[c*4+3], kv.w, a4.w);
            }
            float s = (a4.x + a4.y) + (a4.z + a4.w);
            if (fl[jj] != 0.f) s = -10000.f;       // literal reference semantics
            const float4* vp4 = reinterpret_cast<const float4*>(&vs[jj][0]);
            if (s <= m) {
                float p = __expf(s - m);
                l += p;
                #pragma unroll
                for (int c = 0; c < 16; ++c) {
                    float4 vv = vp4[c];
                    o[c*4+0] = fmaf(p, vv.x, o[c*4+0]);
                    o[c*4+1] = fmaf(p, vv.y, o[c*4+1]);
                    o[c*4+2] = fmaf(p, vv.z, o[c*4+2]);
                    o[c*4+3] = fmaf(p, vv.w, o[c*4+3]);
                }
            } else {
                float cc = __expf(m - s);
                l = fmaf(l, cc, 1.0f);
                #pragma unroll
                for (int c = 0; c < 16; ++c) {
                    float4 vv = vp4[c];
                    o[c*4+0] = fmaf(o[c*4+0], cc, vv.x);
                    o[c*4+1] = fmaf(o[c*4+1], cc, vv.y);
                    o[c*4+2] = fmaf(o[c*4+2], cc, vv.z);
                    o[c*4+3] = fmaf(o[c*4+3], cc, vv.w);
                }
                m = s;
            }
        }
    }

    // merge the two halves (lanes t and t^32)
    float m2 = __shfl_xor(m, 32);
    float M  = fmaxf(m, m2);
    float sa = __expf(m - M);
    float sb = __expf(m2 - M);
    float l2 = __shfl_xor(l, 32);
    float L  = l * sa + l2 * sb;
    #pragma unroll
    for (int d = 0; d < 64; ++d) {
        float o2 = __shfl_xor(o[d], 32);
        o[d] = o[d] * sa + o2 * sb;
    }

    if (t < 32) {
        int idx = ((b * Hc + h) * 8 + chunk) * Gc + qidx;
        pm[idx] = M;
        pl[idx] = L;
        #pragma unroll
        for (int d = 0; d < 64; ++d) po[(size_t)idx * 64 + d] = o[d];
    }
}

// ---------------------------------------------------------------------------
// Kernel 4: combine 8 chunk-partials -> out rows [0, G)
// grid (G, H, B), block 64 (lane = dim).
// ---------------------------------------------------------------------------
__global__ void global_combine(const float* __restrict__ pm, const float* __restrict__ pl,
                               const float* __restrict__ po, float* __restrict__ out)
{
    const int d = threadIdx.x;
    const int g = blockIdx.x;
    const int h = blockIdx.y;
    const int b = blockIdx.z;
    const int base = ((b * Hc + h) * 8) * Gc + g;

    float M = -3.0e38f;
    #pragma unroll
    for (int c = 0; c < 8; ++c) M = fmaxf(M, pm[base + c * Gc]);
    float L = 0.f, O = 0.f;
    #pragma unroll
    for (int c = 0; c < 8; ++c) {
        float w = __expf(pm[base + c * Gc] - M);
        L = fmaf(pl[base + c * Gc], w, L);
        O = fmaf(po[(size_t)(base + c * Gc) * 64 + d], w, O);
    }
    out[((size_t)b * Sc + g) * Ec + h * HDc + d] = O / L;
}

// ---------------------------------------------------------------------------
extern "C" void kernel_launch(void* const* d_in, const int* in_sizes, int n_in,
                              void* d_out, int out_size, void* d_ws, size_t ws_size,
                              hipStream_t stream)
{
    (void)in_sizes; (void)n_in; (void)out_size; (void)ws_size;

    const float* hs   = (const float*)d_in[0];
    const float* msk  = (const float*)d_in[1];
    const float* Wq   = (const float*)d_in[2];
    const float* bq   = (const float*)d_in[3];
    const float* Wk   = (const float*)d_in[4];
    const float* bk   = (const float*)d_in[5];
    const float* Wv   = (const float*)d_in[6];
    const float* bv   = (const float*)d_in[7];
    const float* Wqg  = (const float*)d_in[8];
    const float* bqg  = (const float*)d_in[9];
    const float* Wkg  = (const float*)d_in[10];
    const float* bkg  = (const float*)d_in[11];
    const float* Wvg  = (const float*)d_in[12];
    const float* bvg  = (const float*)d_in[13];
    float* out = (float*)d_out;

    const size_t NPROJ = (size_t)Mtot * Ec;     // 6291456
    float* q  = (float*)d_ws;
    float* k  = q  + NPROJ;
    float* v  = k  + NPROJ;
    float* kg = v  + NPROJ;
    float* vg = kg + NPROJ;
    float* qg = vg + NPROJ;                     // 64*768
    float* pm = qg + (size_t)Bc * Gc * Ec;      // 6144
    float* pl = pm + (size_t)Bc * Hc * 8 * Gc;
    float* po = pl + (size_t)Bc * Hc * 8 * Gc;  // 6144*64

    // 1. projections
    proj_gemm<<<dim3(Mtot / 128, Ec / 128, 5), 256, 0, stream>>>(
        hs, Wq, bq, q, Wk, bk, k, Wv, bv, v, Wkg, bkg, kg, Wvg, bvg, vg);
    // 1b. qg
    qg_kernel<<<dim3((Bc * Gc * Ec) / 256), 256, 0, stream>>>(hs, Wqg, bqg, qg);
    // 2. banded + global-key attention (writes all rows; rows < G overwritten later)
    band_attn<<<dim3(Sc / 64, Hc, Bc), 64, 0, stream>>>(q, k, v, msk, out);
    // 3. global-row attention partials
    global_partial<<<dim3(8, Hc, Bc), 64, 0, stream>>>(qg, kg, vg, msk, pm, pl, po);
    // 4. combine -> rows [0, G)
    global_combine<<<dim3(Gc, Hc, Bc), 64, 0, stream>>>(pm, pl, po, out);
}

// Round 3
// 1386.941 us; speedup vs baseline: 1.3195x; 1.3195x over previous
//
#include <hip/hip_runtime.h>
#include <hip/hip_bf16.h>

// Problem constants
#define Bc 2
#define Sc 4096
#define Ec 768
#define Hc 12
#define HDc 64
#define Wc 256
#define Gc 32
#define Mtot (Bc*Sc)   // 8192
#define NCH 16         // global-attn key chunks (256 keys each)

// ---------------------------------------------------------------------------
// Kernel 1: fused projection GEMMs.  C_z = hs @ W_z + b_z (q scaled by 0.125)
// grid (64, 6, 5), block 256.  128x128 tile, BK=16, 8x8 per thread.
// ---------------------------------------------------------------------------
__global__ __launch_bounds__(256) void proj_gemm(
    const float* __restrict__ A,
    const float* __restrict__ Wq,  const float* __restrict__ bq,  float* __restrict__ Cq,
    const float* __restrict__ Wk,  const float* __restrict__ bk,  float* __restrict__ Ck,
    const float* __restrict__ Wv,  const float* __restrict__ bv,  float* __restrict__ Cv,
    const float* __restrict__ Wkg, const float* __restrict__ bkg, float* __restrict__ Ckg,
    const float* __restrict__ Wvg, const float* __restrict__ bvg, float* __restrict__ Cvg)
{
    const int z = blockIdx.z;
    const float* Wm; const float* bias; float* C; float scale = 1.0f;
    switch (z) {
        case 0:  Wm = Wq;  bias = bq;  C = Cq; scale = 0.125f; break;
        case 1:  Wm = Wk;  bias = bk;  C = Ck;  break;
        case 2:  Wm = Wv;  bias = bv;  C = Cv;  break;
        case 3:  Wm = Wkg; bias = bkg; C = Ckg; break;
        default: Wm = Wvg; bias = bvg; C = Cvg; break;
    }

    __shared__ float As[16][132];   // [k][m], padded
    __shared__ float Bs[16][132];   // [k][n], padded

    const int tid = threadIdx.x;
    const int m0 = blockIdx.x * 128;
    const int n0 = blockIdx.y * 128;
    const int tm = (tid >> 4) * 8;
    const int tn = (tid & 15) * 8;

    float acc[8][8];
    #pragma unroll
    for (int i = 0; i < 8; ++i)
        #pragma unroll
        for (int j = 0; j < 8; ++j) acc[i][j] = 0.f;

    for (int k0 = 0; k0 < Ec; k0 += 16) {
        #pragma unroll
        for (int l = 0; l < 2; ++l) {
            int id  = tid + l * 256;
            int row = id >> 2;
            int c4  = (id & 3) * 4;
            float4 av = *reinterpret_cast<const float4*>(&A[(size_t)(m0 + row) * Ec + k0 + c4]);
            As[c4 + 0][row] = av.x;
            As[c4 + 1][row] = av.y;
            As[c4 + 2][row] = av.z;
            As[c4 + 3][row] = av.w;
        }
        #pragma unroll
        for (int l = 0; l < 2; ++l) {
            int id  = tid + l * 256;
            int row = id >> 5;
            int c4  = (id & 31) * 4;
            *reinterpret_cast<float4*>(&Bs[row][c4]) =
                *reinterpret_cast<const float4*>(&Wm[(size_t)(k0 + row) * Ec + n0 + c4]);
        }
        __syncthreads();
        #pragma unroll
        for (int kk = 0; kk < 16; ++kk) {
            float a[8], b[8];
            #pragma unroll
            for (int i = 0; i < 8; ++i) a[i] = As[kk][tm + i];
            #pragma unroll
            for (int j = 0; j < 8; ++j) b[j] = Bs[kk][tn + j];
            #pragma unroll
            for (int i = 0; i < 8; ++i)
                #pragma unroll
                for (int j = 0; j < 8; ++j)
                    acc[i][j] = fmaf(a[i], b[j], acc[i][j]);
        }
        __syncthreads();
    }

    #pragma unroll
    for (int i = 0; i < 8; ++i) {
        float r[8];
        #pragma unroll
        for (int j = 0; j < 8; ++j)
            r[j] = (acc[i][j] + bias[n0 + tn + j]) * scale;
        float4 o0 = { r[0], r[1], r[2], r[3] };
        float4 o1 = { r[4], r[5], r[6], r[7] };
        float* cp = &C[(size_t)(m0 + tm + i) * Ec + n0 + tn];
        *reinterpret_cast<float4*>(cp)     = o0;
        *reinterpret_cast<float4*>(cp + 4) = o1;
    }
}

// ---------------------------------------------------------------------------
// Kernel 1b: qg = (hs[:, :G] @ Wqg + bqg) * 0.125  -- tiny (64 x 768)
// ---------------------------------------------------------------------------
__global__ void qg_kernel(const float* __restrict__ hs, const float* __restrict__ Wqg,
                          const float* __restrict__ bqg, float* __restrict__ qg)
{
    int idx = blockIdx.x * 256 + threadIdx.x;
    int r = idx / Ec, n = idx - r * Ec;
    int b = r >> 5, g = r & 31;
    const float* a = &hs[(size_t)(b * Sc + g) * Ec];
    float s0 = 0.f, s1 = 0.f, s2 = 0.f, s3 = 0.f;
    for (int k2 = 0; k2 < Ec; k2 += 4) {
        s0 = fmaf(a[k2 + 0], Wqg[(size_t)(k2 + 0) * Ec + n], s0);
        s1 = fmaf(a[k2 + 1], Wqg[(size_t)(k2 + 1) * Ec + n], s1);
        s2 = fmaf(a[k2 + 2], Wqg[(size_t)(k2 + 2) * Ec + n], s2);
        s3 = fmaf(a[k2 + 3], Wqg[(size_t)(k2 + 3) * Ec + n], s3);
    }
    qg[idx] = ((s0 + s1) + (s2 + s3) + bqg[n]) * 0.125f;
}

// ---------------------------------------------------------------------------
// Kernel 2 v2: banded sliding-window attention + 32 global-key scores.
// grid (S/256, H, B), block 256 (4 waves).  Wave w owns queries
// [i0+64w, i0+64w+64); lane = query.  13 staged K/V tiles shared by all
// waves; wave w consumes window tiles w..w+8 plus the global tile.
// Defer-max online softmax (m0=0, THR=8) -> rescale branch ~never taken,
// wave-uniform via __any.  Invalid/masked keys contribute exp(-1e9)=0.
// ---------------------------------------------------------------------------
__global__ __launch_bounds__(256) void band_attn(
    const float* __restrict__ q, const float* __restrict__ k, const float* __restrict__ v,
    const float* __restrict__ mask, float* __restrict__ out)
{
    const int tid = threadIdx.x;
    const int w   = tid >> 6;            // wave 0..3
    const int t   = tid & 63;            // lane = query slot
    const int i0  = blockIdx.x * 256;
    const int h   = blockIdx.y;
    const int b   = blockIdx.z;
    const int i   = i0 + w * 64 + t;     // absolute query index

    __shared__ float ks[64][64];
    __shared__ float vs[64][64];
    __shared__ float fm[64];

    const size_t base = ((size_t)b * Sc) * Ec + (size_t)h * HDc;

    float qr[64];
    {
        const float* qp = &q[base + (size_t)i * Ec];
        #pragma unroll
        for (int c = 0; c < 16; ++c) {
            float4 t4 = *reinterpret_cast<const float4*>(&qp[c * 4]);
            qr[c*4+0] = t4.x; qr[c*4+1] = t4.y; qr[c*4+2] = t4.z; qr[c*4+3] = t4.w;
        }
    }

    float m = 0.f, l = 0.f;              // defer-max: m fixed at 0 unless s > m+8
    float o[64];
    #pragma unroll
    for (int d = 0; d < 64; ++d) o[d] = 0.f;

    // stage 0: global keys [0,32); stages 1..12: window tile ti = st-1,
    // j0 = i0 - 256 + ti*64.
    for (int st = 0; st < 13; ++st) {
        const bool is_g = (st == 0);
        const int  ti   = st - 1;
        const int  j0   = is_g ? 0 : (i0 - Wc + ti * 64);
        const int  rows = is_g ? Gc : 64;

        __syncthreads();
        // stage K/V tile: 64 rows x 64 cols, 1024 float4 each, 4 per thread
        #pragma unroll
        for (int l4 = 0; l4 < 4; ++l4) {
            int id  = tid + l4 * 256;
            int row = id >> 4;
            int c4  = (id & 15) * 4;
            int j   = j0 + row;
            float4 kv = {0.f, 0.f, 0.f, 0.f};
            float4 vv = {0.f, 0.f, 0.f, 0.f};
            if (row < rows && j >= 0 && j < Sc) {
                kv = *reinterpret_cast<const float4*>(&k[base + (size_t)j * Ec + c4]);
                vv = *reinterpret_cast<const float4*>(&v[base + (size_t)j * Ec + c4]);
            }
            *reinterpret_cast<float4*>(&ks[row][c4]) = kv;
            *reinterpret_cast<float4*>(&vs[row][c4]) = vv;
        }
        if (tid < 64) {
            int j = j0 + tid;
            float f;
            if (is_g) f = 0.f;                       // global keys unmasked
            else if (j < 0 || j >= Sc) f = -1.0e9f;  // out of sequence
            else f = (mask[b * Sc + j] != 0.f) ? -10000.f : 0.f;
            fm[tid] = f;
        }
        __syncthreads();

        const bool active = is_g || (ti >= w && ti <= w + 8);
        if (!active) continue;

        for (int jj = 0; jj < rows; ++jj) {
            const int j = j0 + jj;
            const float4* kp4 = reinterpret_cast<const float4*>(&ks[jj][0]);
            float4 a4 = {0.f, 0.f, 0.f, 0.f};
            #pragma unroll
            for (int c = 0; c < 16; ++c) {
                float4 kv = kp4[c];
                a4.x = fmaf(qr[c*4+0], kv.x, a4.x);
                a4.y = fmaf(qr[c*4+1], kv.y, a4.y);
                a4.z = fmaf(qr[c*4+2], kv.z, a4.z);
                a4.w = fmaf(qr[c*4+3], kv.w, a4.w);
            }
            float s = (a4.x + a4.y) + (a4.z + a4.w);
            if (!is_g) {
                s += fm[jj];
                bool inwin = (j >= i - Wc) && (j <= i + Wc);
                s = inwin ? s : -1.0e9f;
            }
            if (__any(s > m + 8.0f)) {               // ~never taken
                float nm = fmaxf(m, s);
                float cc = __expf(m - nm);
                l *= cc;
                #pragma unroll
                for (int d = 0; d < 64; ++d) o[d] *= cc;
                m = nm;
            }
            float p = __expf(s - m);
            l += p;
            if (__any(p > 0.f)) {
                const float4* vp4 = reinterpret_cast<const float4*>(&vs[jj][0]);
                #pragma unroll
                for (int c = 0; c < 16; ++c) {
                    float4 vv = vp4[c];
                    o[c*4+0] = fmaf(p, vv.x, o[c*4+0]);
                    o[c*4+1] = fmaf(p, vv.y, o[c*4+1]);
                    o[c*4+2] = fmaf(p, vv.z, o[c*4+2]);
                    o[c*4+3] = fmaf(p, vv.w, o[c*4+3]);
                }
            }
        }
    }

    float rinv = 1.0f / l;
    float* op = &out[base + (size_t)i * Ec];
    #pragma unroll
    for (int c = 0; c < 16; ++c) {
        float4 t4 = { o[c*4+0]*rinv, o[c*4+1]*rinv, o[c*4+2]*rinv, o[c*4+3]*rinv };
        *reinterpret_cast<float4*>(&op[c * 4]) = t4;
    }
}

// ---------------------------------------------------------------------------
// Kernel 3: global-row attention, partials over NCH chunks of S/NCH keys.
// grid (NCH, H, B), block 64.  Lane = query(0..31) + 32*half.
// ---------------------------------------------------------------------------
__global__ __launch_bounds__(64, 2) void global_partial(
    const float* __restrict__ qg, const float* __restrict__ kg, const float* __restrict__ vg,
    const float* __restrict__ mask,
    float* __restrict__ pm, float* __restrict__ pl, float* __restrict__ po)
{
    const int t     = threadIdx.x;
    const int qidx  = t & 31;
    const int half  = t >> 5;
    const int chunk = blockIdx.x;   // 0..NCH-1
    const int h     = blockIdx.y;
    const int b     = blockIdx.z;

    __shared__ float ks[64][64];
    __shared__ float vs[64][64];
    __shared__ float fl[64];

    const size_t kbase = ((size_t)b * Sc) * Ec + (size_t)h * HDc;

    float qr[64];
    {
        const float* qp = &qg[(size_t)(b * Gc + qidx) * Ec + h * HDc];
        #pragma unroll
        for (int c = 0; c < 16; ++c) {
            float4 t4 = *reinterpret_cast<const float4*>(&qp[c * 4]);
            qr[c*4+0] = t4.x; qr[c*4+1] = t4.y; qr[c*4+2] = t4.z; qr[c*4+3] = t4.w;
        }
    }

    float m = 0.f, l = 0.f;
    float o[64];
    #pragma unroll
    for (int d = 0; d < 64; ++d) o[d] = 0.f;

    const int c0 = chunk * (Sc / NCH);
    for (int tt = 0; tt < (Sc / NCH) / 64; ++tt) {
        const int j0 = c0 + tt * 64;
        __syncthreads();
        #pragma unroll
        for (int r4 = 0; r4 < 16; ++r4) {
            int id  = r4 * 64 + t;
            int row = id >> 4;
            int c4  = (id & 15) * 4;
            int j   = j0 + row;
            *reinterpret_cast<float4*>(&ks[row][c4]) =
                *reinterpret_cast<const float4*>(&kg[kbase + (size_t)j * Ec + c4]);
            *reinterpret_cast<float4*>(&vs[row][c4]) =
                *reinterpret_cast<const float4*>(&vg[kbase + (size_t)j * Ec + c4]);
        }
        {
            int j = j0 + t;
            fl[t] = (mask[b * Sc + j] < 0.f) ? 1.f : 0.f;
        }
        __syncthreads();

        for (int jj2 = 0; jj2 < 32; ++jj2) {
            int jj = half + 2 * jj2;
            const float4* kp4 = reinterpret_cast<const float4*>(&ks[jj][0]);
            float4 a4 = {0.f, 0.f, 0.f, 0.f};
            #pragma unroll
            for (int c = 0; c < 16; ++c) {
                float4 kv = kp4[c];
                a4.x = fmaf(qr[c*4+0], kv.x, a4.x);
                a4.y = fmaf(qr[c*4+1], kv.y, a4.y);
                a4.z = fmaf(qr[c*4+2], kv.z, a4.z);
                a4.w = fmaf(qr[c*4+3], kv.w, a4.w);
            }
            float s = (a4.x + a4.y) + (a4.z + a4.w);
            if (fl[jj] != 0.f) s = -10000.f;
            if (__any(s > m + 8.0f)) {
                float nm = fmaxf(m, s);
                float cc = __expf(m - nm);
                l *= cc;
                #pragma unroll
                for (int d = 0; d < 64; ++d) o[d] *= cc;
                m = nm;
            }
            float p = __expf(s - m);
            l += p;
            const float4* vp4 = reinterpret_cast<const float4*>(&vs[jj][0]);
            #pragma unroll
            for (int c = 0; c < 16; ++c) {
                float4 vv = vp4[c];
                o[c*4+0] = fmaf(p, vv.x, o[c*4+0]);
                o[c*4+1] = fmaf(p, vv.y, o[c*4+1]);
                o[c*4+2] = fmaf(p, vv.z, o[c*4+2]);
                o[c*4+3] = fmaf(p, vv.w, o[c*4+3]);
            }
        }
    }

    // merge the two key-halves (lanes t and t^32)
    float m2 = __shfl_xor(m, 32);
    float M  = fmaxf(m, m2);
    float sa = __expf(m - M);
    float sb = __expf(m2 - M);
    float l2 = __shfl_xor(l, 32);
    float L  = l * sa + l2 * sb;
    #pragma unroll
    for (int d = 0; d < 64; ++d) {
        float o2 = __shfl_xor(o[d], 32);
        o[d] = o[d] * sa + o2 * sb;
    }

    if (t < 32) {
        int idx = ((b * Hc + h) * NCH + chunk) * Gc + qidx;
        pm[idx] = M;
        pl[idx] = L;
        #pragma unroll
        for (int d = 0; d < 64; ++d) po[(size_t)idx * 64 + d] = o[d];
    }
}

// ---------------------------------------------------------------------------
// Kernel 4: combine NCH chunk-partials -> out rows [0, G)
// ---------------------------------------------------------------------------
__global__ void global_combine(const float* __restrict__ pm, const float* __restrict__ pl,
                               const float* __restrict__ po, float* __restrict__ out)
{
    const int d = threadIdx.x;
    const int g = blockIdx.x;
    const int h = blockIdx.y;
    const int b = blockIdx.z;
    const int base = ((b * Hc + h) * NCH) * Gc + g;

    float M = -3.0e38f;
    #pragma unroll
    for (int c = 0; c < NCH; ++c) M = fmaxf(M, pm[base + c * Gc]);
    float L = 0.f, O = 0.f;
    #pragma unroll
    for (int c = 0; c < NCH; ++c) {
        float w = __expf(pm[base + c * Gc] - M);
        L = fmaf(pl[base + c * Gc], w, L);
        O = fmaf(po[(size_t)(base + c * Gc) * 64 + d], w, O);
    }
    out[((size_t)b * Sc + g) * Ec + h * HDc + d] = O / L;
}

// ---------------------------------------------------------------------------
extern "C" void kernel_launch(void* const* d_in, const int* in_sizes, int n_in,
                              void* d_out, int out_size, void* d_ws, size_t ws_size,
                              hipStream_t stream)
{
    (void)in_sizes; (void)n_in; (void)out_size; (void)ws_size;

    const float* hs   = (const float*)d_in[0];
    const float* msk  = (const float*)d_in[1];
    const float* Wq   = (const float*)d_in[2];
    const float* bq   = (const float*)d_in[3];
    const float* Wk   = (const float*)d_in[4];
    const float* bk   = (const float*)d_in[5];
    const float* Wv   = (const float*)d_in[6];
    const float* bv   = (const float*)d_in[7];
    const float* Wqg  = (const float*)d_in[8];
    const float* bqg  = (const float*)d_in[9];
    const float* Wkg  = (const float*)d_in[10];
    const float* bkg  = (const float*)d_in[11];
    const float* Wvg  = (const float*)d_in[12];
    const float* bvg  = (const float*)d_in[13];
    float* out = (float*)d_out;

    const size_t NPROJ = (size_t)Mtot * Ec;     // 6291456
    float* q  = (float*)d_ws;
    float* k  = q  + NPROJ;
    float* v  = k  + NPROJ;
    float* kg = v  + NPROJ;
    float* vg = kg + NPROJ;
    float* qg = vg + NPROJ;                     // 64*768
    float* pm = qg + (size_t)Bc * Gc * Ec;
    float* pl = pm + (size_t)Bc * Hc * NCH * Gc;
    float* po = pl + (size_t)Bc * Hc * NCH * Gc;

    // 1. projections
    proj_gemm<<<dim3(Mtot / 128, Ec / 128, 5), 256, 0, stream>>>(
        hs, Wq, bq, q, Wk, bk, k, Wv, bv, v, Wkg, bkg, kg, Wvg, bvg, vg);
    // 1b. qg
    qg_kernel<<<dim3((Bc * Gc * Ec) / 256), 256, 0, stream>>>(hs, Wqg, bqg, qg);
    // 2. banded + global-key attention (writes all rows; rows < G overwritten later)
    band_attn<<<dim3(Sc / 256, Hc, Bc), 256, 0, stream>>>(q, k, v, msk, out);
    // 3. global-row attention partials
    global_partial<<<dim3(NCH, Hc, Bc), 64, 0, stream>>>(qg, kg, vg, msk, pm, pl, po);
    // 4. combine -> rows [0, G)
    global_combine<<<dim3(Gc, Hc, Bc), 64, 0, stream>>>(pm, pl, po, out);
}

// Round 4
// 1193.532 us; speedup vs baseline: 1.5333x; 1.1620x over previous
//
#include <hip/hip_runtime.h>
#include <hip/hip_bf16.h>

// Problem constants
#define Bc 2
#define Sc 4096
#define Ec 768
#define Hc 12
#define HDc 64
#define Wc 256
#define Gc 32
#define Mtot (Bc*Sc)   // 8192
#define NCH 32         // global-attn key chunks (128 keys each)

typedef unsigned short ushort;
typedef __attribute__((ext_vector_type(8))) short short8v;   // 8 bf16 (4 VGPR)
typedef __attribute__((ext_vector_type(4))) float f32x4;     // MFMA acc

__device__ __forceinline__ ushort f2bf(float x) {
    __hip_bfloat16 h = __float2bfloat16(x);
    return *reinterpret_cast<ushort*>(&h);
}
__device__ __forceinline__ float bf2f(ushort u) {
    __hip_bfloat16 h;
    *reinterpret_cast<ushort*>(&h) = u;
    return __bfloat162float(h);
}

__device__ __forceinline__ void gl2lds16(const void* g, void* l) {
    __builtin_amdgcn_global_load_lds(
        (const __attribute__((address_space(1))) void*)g,
        (__attribute__((address_space(3))) void*)l, 16, 0, 0);
}

// ---------------------------------------------------------------------------
// Prep A: split hs (fp32) -> Ah, Al (bf16), elementwise.  id = one float4.
// ---------------------------------------------------------------------------
__global__ void split_a(const float* __restrict__ x, ushort* __restrict__ hi,
                        ushort* __restrict__ lo)
{
    int id = blockIdx.x * 256 + threadIdx.x;
    float4 v = reinterpret_cast<const float4*>(x)[id];
    float c[4] = {v.x, v.y, v.z, v.w};
    ushort h[4], l[4];
    #pragma unroll
    for (int u = 0; u < 4; ++u) {
        h[u] = f2bf(c[u]);
        l[u] = f2bf(c[u] - bf2f(h[u]));
    }
    typedef __attribute__((ext_vector_type(4))) ushort us4;
    us4 hv = {h[0], h[1], h[2], h[3]};
    us4 lv = {l[0], l[1], l[2], l[3]};
    reinterpret_cast<us4*>(hi)[id] = hv;
    reinterpret_cast<us4*>(lo)[id] = lv;
}

// ---------------------------------------------------------------------------
// Prep B: per weight z: WTh[n][k] = bf16(W[k][n]), WTl = residual. (transpose)
// grid (768*768/256, 5)
// ---------------------------------------------------------------------------
__global__ void split_wt(const float* __restrict__ W0, const float* __restrict__ W1,
                         const float* __restrict__ W2, const float* __restrict__ W3,
                         const float* __restrict__ W4,
                         ushort* __restrict__ hi, ushort* __restrict__ lo)
{
    const int z = blockIdx.y;
    const float* W;
    switch (z) {
        case 0: W = W0; break; case 1: W = W1; break; case 2: W = W2; break;
        case 3: W = W3; break; default: W = W4; break;
    }
    int id = blockIdx.x * 256 + threadIdx.x;     // id = n*768 + k
    int n = id / Ec, kk = id - n * Ec;
    float x = W[(size_t)kk * Ec + n];
    ushort h = f2bf(x);
    ushort l = f2bf(x - bf2f(h));
    size_t o = (size_t)z * Ec * Ec + id;
    hi[o] = h;
    lo[o] = l;
}

// ---------------------------------------------------------------------------
// Kernel 1 (MFMA): C_z = hs @ W_z + b_z (q scaled by 0.125), bf16 3-term split.
// grid (64, 6, 5), block 256 (4 waves).  128x128 tile, BK=32.
// LDS rows 128B: slots 0-3 = hi k-groups, 4-7 = lo; phys slot = s ^ (row&7).
// ---------------------------------------------------------------------------
__global__ __launch_bounds__(256) void proj_mfma(
    const ushort* __restrict__ Ah, const ushort* __restrict__ Al,
    const ushort* __restrict__ WTh, const ushort* __restrict__ WTl,
    const float* __restrict__ bq,  const float* __restrict__ bk,
    const float* __restrict__ bv,  const float* __restrict__ bkg,
    const float* __restrict__ bvg,
    float* __restrict__ Cq, float* __restrict__ Ck, float* __restrict__ Cv,
    float* __restrict__ Ckg, float* __restrict__ Cvg)
{
    const int z = blockIdx.z;
    const float* bias; float* C; float scale = 1.0f;
    switch (z) {
        case 0:  bias = bq;  C = Cq; scale = 0.125f; break;
        case 1:  bias = bk;  C = Ck;  break;
        case 2:  bias = bv;  C = Cv;  break;
        case 3:  bias = bkg; C = Ckg; break;
        default: bias = bvg; C = Cvg; break;
    }
    const ushort* Bh = WTh + (size_t)z * Ec * Ec;
    const ushort* Bl = WTl + (size_t)z * Ec * Ec;

    __shared__ __align__(16) char smem[32768];   // [0,16K)=A, [16K,32K)=B

    const int tid = threadIdx.x;
    const int w   = tid >> 6;          // wave
    const int lane = tid & 63;
    const int wr  = w >> 1, wc = w & 1;   // wave subtile (row, col) of 64x64
    const int lr  = lane & 15, kg = lane >> 4;
    const int m0  = blockIdx.x * 128;
    const int n0  = blockIdx.y * 128;

    f32x4 acc[4][4];
    #pragma unroll
    for (int i = 0; i < 4; ++i)
        #pragma unroll
        for (int j = 0; j < 4; ++j) acc[i][j] = (f32x4){0.f, 0.f, 0.f, 0.f};

    for (int k0 = 0; k0 < Ec; k0 += 32) {
        // stage A (16KB) + B (16KB): 1024 16B segs each, 4 issues per thread ea.
        #pragma unroll
        for (int it = 0; it < 4; ++it) {
            int id = it * 256 + tid;
            int r  = id >> 3;           // local row 0..127
            int ls = (id & 7) ^ (r & 7);
            const ushort* src = (ls < 4)
                ? Ah + ((size_t)(m0 + r) * Ec + k0 + ls * 8)
                : Al + ((size_t)(m0 + r) * Ec + k0 + (ls - 4) * 8);
            gl2lds16(src, smem + id * 16);
        }
        #pragma unroll
        for (int it = 0; it < 4; ++it) {
            int id = it * 256 + tid;
            int r  = id >> 3;
            int ls = (id & 7) ^ (r & 7);
            const ushort* src = (ls < 4)
                ? Bh + ((size_t)(n0 + r) * Ec + k0 + ls * 8)
                : Bl + ((size_t)(n0 + r) * Ec + k0 + (ls - 4) * 8);
            gl2lds16(src, smem + 16384 + id * 16);
        }
        __syncthreads();

        short8v ah[4], al[4], bh[4], bl[4];
        #pragma unroll
        for (int f = 0; f < 4; ++f) {
            int ra = wr * 64 + f * 16 + lr;
            int ba = ra * 128;
            ah[f] = *reinterpret_cast<const short8v*>(smem + ba + ((kg ^ (ra & 7)) << 4));
            al[f] = *reinterpret_cast<const short8v*>(smem + ba + (((kg + 4) ^ (ra & 7)) << 4));
            int rb = wc * 64 + f * 16 + lr;
            int bb = 16384 + rb * 128;
            bh[f] = *reinterpret_cast<const short8v*>(smem + bb + ((kg ^ (rb & 7)) << 4));
            bl[f] = *reinterpret_cast<const short8v*>(smem + bb + (((kg + 4) ^ (rb & 7)) << 4));
        }
        #pragma unroll
        for (int fi = 0; fi < 4; ++fi)
            #pragma unroll
            for (int fj = 0; fj < 4; ++fj) {
                acc[fi][fj] = __builtin_amdgcn_mfma_f32_16x16x32_bf16(ah[fi], bh[fj], acc[fi][fj], 0, 0, 0);
                acc[fi][fj] = __builtin_amdgcn_mfma_f32_16x16x32_bf16(ah[fi], bl[fj], acc[fi][fj], 0, 0, 0);
                acc[fi][fj] = __builtin_amdgcn_mfma_f32_16x16x32_bf16(al[fi], bh[fj], acc[fi][fj], 0, 0, 0);
            }
        __syncthreads();
    }

    // epilogue: C/D map col = lane&15, row = (lane>>4)*4 + r  [m89/m91]
    #pragma unroll
    for (int fj = 0; fj < 4; ++fj) {
        int col = n0 + wc * 64 + fj * 16 + lr;
        float bsc = bias[col];
        #pragma unroll
        for (int fi = 0; fi < 4; ++fi) {
            int row0 = m0 + wr * 64 + fi * 16 + kg * 4;
            #pragma unroll
            for (int r = 0; r < 4; ++r)
                C[(size_t)(row0 + r) * Ec + col] = (acc[fi][fj][r] + bsc) * scale;
        }
    }
}

// ---------------------------------------------------------------------------
// Kernel 1 fallback (fp32), used if workspace too small for bf16 buffers.
// ---------------------------------------------------------------------------
__global__ __launch_bounds__(256) void proj_gemm(
    const float* __restrict__ A,
    const float* __restrict__ Wq,  const float* __restrict__ bq,  float* __restrict__ Cq,
    const float* __restrict__ Wk,  const float* __restrict__ bk,  float* __restrict__ Ck,
    const float* __restrict__ Wv,  const float* __restrict__ bv,  float* __restrict__ Cv,
    const float* __restrict__ Wkg, const float* __restrict__ bkg, float* __restrict__ Ckg,
    const float* __restrict__ Wvg, const float* __restrict__ bvg, float* __restrict__ Cvg)
{
    const int z = blockIdx.z;
    const float* Wm; const float* bias; float* C; float scale = 1.0f;
    switch (z) {
        case 0:  Wm = Wq;  bias = bq;  C = Cq; scale = 0.125f; break;
        case 1:  Wm = Wk;  bias = bk;  C = Ck;  break;
        case 2:  Wm = Wv;  bias = bv;  C = Cv;  break;
        case 3:  Wm = Wkg; bias = bkg; C = Ckg; break;
        default: Wm = Wvg; bias = bvg; C = Cvg; break;
    }
    __shared__ float As[16][132];
    __shared__ float Bs[16][132];
    const int tid = threadIdx.x;
    const int m0 = blockIdx.x * 128;
    const int n0 = blockIdx.y * 128;
    const int tm = (tid >> 4) * 8;
    const int tn = (tid & 15) * 8;
    float acc[8][8];
    #pragma unroll
    for (int i = 0; i < 8; ++i)
        #pragma unroll
        for (int j = 0; j < 8; ++j) acc[i][j] = 0.f;
    for (int k0 = 0; k0 < Ec; k0 += 16) {
        #pragma unroll
        for (int l = 0; l < 2; ++l) {
            int id  = tid + l * 256;
            int row = id >> 2;
            int c4  = (id & 3) * 4;
            float4 av = *reinterpret_cast<const float4*>(&A[(size_t)(m0 + row) * Ec + k0 + c4]);
            As[c4 + 0][row] = av.x; As[c4 + 1][row] = av.y;
            As[c4 + 2][row] = av.z; As[c4 + 3][row] = av.w;
        }
        #pragma unroll
        for (int l = 0; l < 2; ++l) {
            int id  = tid + l * 256;
            int row = id >> 5;
            int c4  = (id & 31) * 4;
            *reinterpret_cast<float4*>(&Bs[row][c4]) =
                *reinterpret_cast<const float4*>(&Wm[(size_t)(k0 + row) * Ec + n0 + c4]);
        }
        __syncthreads();
        #pragma unroll
        for (int kk = 0; kk < 16; ++kk) {
            float a[8], b[8];
            #pragma unroll
            for (int i = 0; i < 8; ++i) a[i] = As[kk][tm + i];
            #pragma unroll
            for (int j = 0; j < 8; ++j) b[j] = Bs[kk][tn + j];
            #pragma unroll
            for (int i = 0; i < 8; ++i)
                #pragma unroll
                for (int j = 0; j < 8; ++j)
                    acc[i][j] = fmaf(a[i], b[j], acc[i][j]);
        }
        __syncthreads();
    }
    #pragma unroll
    for (int i = 0; i < 8; ++i) {
        float r[8];
        #pragma unroll
        for (int j = 0; j < 8; ++j)
            r[j] = (acc[i][j] + bias[n0 + tn + j]) * scale;
        float4 o0 = { r[0], r[1], r[2], r[3] };
        float4 o1 = { r[4], r[5], r[6], r[7] };
        float* cp = &C[(size_t)(m0 + tm + i) * Ec + n0 + tn];
        *reinterpret_cast<float4*>(cp)     = o0;
        *reinterpret_cast<float4*>(cp + 4) = o1;
    }
}

// ---------------------------------------------------------------------------
// Kernel 1b: qg = (hs[:, :G] @ Wqg + bqg) * 0.125  -- tiny (64 x 768)
// ---------------------------------------------------------------------------
__global__ void qg_kernel(const float* __restrict__ hs, const float* __restrict__ Wqg,
                          const float* __restrict__ bqg, float* __restrict__ qg)
{
    int idx = blockIdx.x * 256 + threadIdx.x;
    int r = idx / Ec, n = idx - r * Ec;
    int b = r >> 5, g = r & 31;
    const float* a = &hs[(size_t)(b * Sc + g) * Ec];
    float s0 = 0.f, s1 = 0.f, s2 = 0.f, s3 = 0.f;
    for (int k2 = 0; k2 < Ec; k2 += 4) {
        s0 = fmaf(a[k2 + 0], Wqg[(size_t)(k2 + 0) * Ec + n], s0);
        s1 = fmaf(a[k2 + 1], Wqg[(size_t)(k2 + 1) * Ec + n], s1);
        s2 = fmaf(a[k2 + 2], Wqg[(size_t)(k2 + 2) * Ec + n], s2);
        s3 = fmaf(a[k2 + 3], Wqg[(size_t)(k2 + 3) * Ec + n], s3);
    }
    qg[idx] = ((s0 + s1) + (s2 + s3) + bqg[n]) * 0.125f;
}

// ---------------------------------------------------------------------------
// Kernel 2 v3: banded + global-key attention, key-split across wave pairs.
// grid (S/128, H, B), block 256 (4 waves).  Block owns 128 queries = 2 groups.
// wave = side*2 + grp:  grp = w&1 (query group), side = w>>1.
//   side 0: window tiles ti in [grp, grp+5)        (320 keys)
//   side 1: window tiles ti in [grp+5, grp+9) + global tile (288 keys)
// Stages: st 0 = global (32 rows), st 1..10 = window tile ti = st-1,
// j0 = i0 - 256 + ti*64.  Defer-max online softmax; merge partials via LDS.
// ---------------------------------------------------------------------------
__global__ __launch_bounds__(256) void band_attn(
    const float* __restrict__ q, const float* __restrict__ k, const float* __restrict__ v,
    const float* __restrict__ mask, float* __restrict__ out)
{
    const int tid  = threadIdx.x;
    const int w    = tid >> 6;
    const int t    = tid & 63;
    const int grp  = w & 1;
    const int side = w >> 1;
    const int i0   = blockIdx.x * 128;
    const int h    = blockIdx.y;
    const int b    = blockIdx.z;
    const int i    = i0 + grp * 64 + t;   // absolute query index

    __shared__ __align__(16) float ks[64][64];
    __shared__ __align__(16) float vs[64][64];
    __shared__ float fm[64];
    __shared__ float pml[2][64], pll[2][64];

    const size_t base = ((size_t)b * Sc) * Ec + (size_t)h * HDc;

    float qr[64];
    {
        const float* qp = &q[base + (size_t)i * Ec];
        #pragma unroll
        for (int c = 0; c < 16; ++c) {
            float4 t4 = *reinterpret_cast<const float4*>(&qp[c * 4]);
            qr[c*4+0] = t4.x; qr[c*4+1] = t4.y; qr[c*4+2] = t4.z; qr[c*4+3] = t4.w;
        }
    }

    float m = 0.f, l = 0.f;               // defer-max baseline 0
    float o[64];
    #pragma unroll
    for (int d = 0; d < 64; ++d) o[d] = 0.f;

    for (int st = 0; st < 11; ++st) {
        const bool is_g = (st == 0);
        const int  ti   = st - 1;
        const int  j0   = is_g ? 0 : (i0 - Wc + ti * 64);
        const int  rows = is_g ? Gc : 64;

        __syncthreads();
        #pragma unroll
        for (int l4 = 0; l4 < 4; ++l4) {
            int id  = tid + l4 * 256;
            int row = id >> 4;
            int c4  = (id & 15) * 4;
            int j   = j0 + row;
            float4 kv = {0.f, 0.f, 0.f, 0.f};
            float4 vv = {0.f, 0.f, 0.f, 0.f};
            if (row < rows && j >= 0 && j < Sc) {
                kv = *reinterpret_cast<const float4*>(&k[base + (size_t)j * Ec + c4]);
                vv = *reinterpret_cast<const float4*>(&v[base + (size_t)j * Ec + c4]);
            }
            *reinterpret_cast<float4*>(&ks[row][c4]) = kv;
            *reinterpret_cast<float4*>(&vs[row][c4]) = vv;
        }
        if (tid < 64) {
            int j = j0 + tid;
            float f;
            if (is_g) f = 0.f;
            else if (j < 0 || j >= Sc) f = -1.0e9f;
            else f = (mask[b * Sc + j] != 0.f) ? -10000.f : 0.f;
            fm[tid] = f;
        }
        __syncthreads();

        const bool active = is_g ? (side == 1)
                                 : (side == 0 ? (ti >= grp && ti <= grp + 4)
                                              : (ti >= grp + 5 && ti <= grp + 8));
        if (!active) continue;

        for (int jj = 0; jj < rows; ++jj) {
            const int j = j0 + jj;
            const float4* kp4 = reinterpret_cast<const float4*>(&ks[jj][0]);
            float4 a4 = {0.f, 0.f, 0.f, 0.f};
            #pragma unroll
            for (int c = 0; c < 16; ++c) {
                float4 kv = kp4[c];
                a4.x = fmaf(qr[c*4+0], kv.x, a4.x);
                a4.y = fmaf(qr[c*4+1], kv.y, a4.y);
                a4.z = fmaf(qr[c*4+2], kv.z, a4.z);
                a4.w = fmaf(qr[c*4+3], kv.w, a4.w);
            }
            float s = (a4.x + a4.y) + (a4.z + a4.w);
            if (!is_g) {
                s += fm[jj];
                bool inwin = (j >= i - Wc) && (j <= i + Wc);
                s = inwin ? s : -1.0e9f;
            }
            if (__any(s > m + 8.0f)) {               // ~never taken
                float nm = fmaxf(m, s);
                float cc = __expf(m - nm);
                l *= cc;
                #pragma unroll
                for (int d = 0; d < 64; ++d) o[d] *= cc;
                m = nm;
            }
            float p = __expf(s - m);
            l += p;
            if (__any(p > 0.f)) {
                const float4* vp4 = reinterpret_cast<const float4*>(&vs[jj][0]);
                #pragma unroll
                for (int c = 0; c < 16; ++c) {
                    float4 vv = vp4[c];
                    o[c*4+0] = fmaf(p, vv.x, o[c*4+0]);
                    o[c*4+1] = fmaf(p, vv.y, o[c*4+1]);
                    o[c*4+2] = fmaf(p, vv.z, o[c*4+2]);
                    o[c*4+3] = fmaf(p, vv.w, o[c*4+3]);
                }
            }
        }
    }

    // merge side-1 partials into side-0, normalize, write out
    __syncthreads();
    if (side == 1) {
        float* dst = (grp == 0) ? &ks[0][0] : &vs[0][0];
        #pragma unroll
        for (int d = 0; d < 64; ++d) dst[(size_t)t * 64 + d] = o[d];
        pml[grp][t] = m;
        pll[grp][t] = l;
    }
    __syncthreads();
    if (side == 0) {
        const float* src = (grp == 0) ? &ks[0][0] : &vs[0][0];
        float mb = pml[grp][t], lb = pll[grp][t];
        float M  = fmaxf(m, mb);
        float ea = __expf(m - M), eb = __expf(mb - M);
        float L  = l * ea + lb * eb;
        float rinv = 1.0f / L;
        float* op = &out[base + (size_t)i * Ec];
        #pragma unroll
        for (int c = 0; c < 16; ++c) {
            float4 ob = *reinterpret_cast<const float4*>(&src[(size_t)t * 64 + c * 4]);
            float4 t4 = { (o[c*4+0]*ea + ob.x*eb) * rinv,
                          (o[c*4+1]*ea + ob.y*eb) * rinv,
                          (o[c*4+2]*ea + ob.z*eb) * rinv,
                          (o[c*4+3]*ea + ob.w*eb) * rinv };
            *reinterpret_cast<float4*>(&op[c * 4]) = t4;
        }
    }
}

// ---------------------------------------------------------------------------
// Kernel 3: global-row attention, partials over NCH chunks of S/NCH keys.
// grid (NCH, H, B), block 64.  Lane = query(0..31) + 32*half.
// ---------------------------------------------------------------------------
__global__ __launch_bounds__(64, 2) void global_partial(
    const float* __restrict__ qg, const float* __restrict__ kg, const float* __restrict__ vg,
    const float* __restrict__ mask,
    float* __restrict__ pm, float* __restrict__ pl, float* __restrict__ po)
{
    const int t     = threadIdx.x;
    const int qidx  = t & 31;
    const int half  = t >> 5;
    const int chunk = blockIdx.x;
    const int h     = blockIdx.y;
    const int b     = blockIdx.z;

    __shared__ float ks[64][64];
    __shared__ float vs[64][64];
    __shared__ float fl[64];

    const size_t kbase = ((size_t)b * Sc) * Ec + (size_t)h * HDc;

    float qr[64];
    {
        const float* qp = &qg[(size_t)(b * Gc + qidx) * Ec + h * HDc];
        #pragma unroll
        for (int c = 0; c < 16; ++c) {
            float4 t4 = *reinterpret_cast<const float4*>(&qp[c * 4]);
            qr[c*4+0] = t4.x; qr[c*4+1] = t4.y; qr[c*4+2] = t4.z; qr[c*4+3] = t4.w;
        }
    }

    float m = 0.f, l = 0.f;
    float o[64];
    #pragma unroll
    for (int d = 0; d < 64; ++d) o[d] = 0.f;

    const int c0 = chunk * (Sc / NCH);
    for (int tt = 0; tt < (Sc / NCH) / 64; ++tt) {
        const int j0 = c0 + tt * 64;
        __syncthreads();
        #pragma unroll
        for (int r4 = 0; r4 < 16; ++r4) {
            int id  = r4 * 64 + t;
            int row = id >> 4;
            int c4  = (id & 15) * 4;
            int j   = j0 + row;
            *reinterpret_cast<float4*>(&ks[row][c4]) =
                *reinterpret_cast<const float4*>(&kg[kbase + (size_t)j * Ec + c4]);
            *reinterpret_cast<float4*>(&vs[row][c4]) =
                *reinterpret_cast<const float4*>(&vg[kbase + (size_t)j * Ec + c4]);
        }
        {
            int j = j0 + t;
            fl[t] = (mask[b * Sc + j] < 0.f) ? 1.f : 0.f;
        }
        __syncthreads();

        for (int jj2 = 0; jj2 < 32; ++jj2) {
            int jj = half + 2 * jj2;
            const float4* kp4 = reinterpret_cast<const float4*>(&ks[jj][0]);
            float4 a4 = {0.f, 0.f, 0.f, 0.f};
            #pragma unroll
            for (int c = 0; c < 16; ++c) {
                float4 kv = kp4[c];
                a4.x = fmaf(qr[c*4+0], kv.x, a4.x);
                a4.y = fmaf(qr[c*4+1], kv.y, a4.y);
                a4.z = fmaf(qr[c*4+2], kv.z, a4.z);
                a4.w = fmaf(qr[c*4+3], kv.w, a4.w);
            }
            float s = (a4.x + a4.y) + (a4.z + a4.w);
            if (fl[jj] != 0.f) s = -10000.f;
            if (__any(s > m + 8.0f)) {
                float nm = fmaxf(m, s);
                float cc = __expf(m - nm);
                l *= cc;
                #pragma unroll
                for (int d = 0; d < 64; ++d) o[d] *= cc;
                m = nm;
            }
            float p = __expf(s - m);
            l += p;
            const float4* vp4 = reinterpret_cast<const float4*>(&vs[jj][0]);
            #pragma unroll
            for (int c = 0; c < 16; ++c) {
                float4 vv = vp4[c];
                o[c*4+0] = fmaf(p, vv.x, o[c*4+0]);
                o[c*4+1] = fmaf(p, vv.y, o[c*4+1]);
                o[c*4+2] = fmaf(p, vv.z, o[c*4+2]);
                o[c*4+3] = fmaf(p, vv.w, o[c*4+3]);
            }
        }
    }

    float m2 = __shfl_xor(m, 32);
    float M  = fmaxf(m, m2);
    float sa = __expf(m - M);
    float sb = __expf(m2 - M);
    float l2 = __shfl_xor(l, 32);
    float L  = l * sa + l2 * sb;
    #pragma unroll
    for (int d = 0; d < 64; ++d) {
        float o2 = __shfl_xor(o[d], 32);
        o[d] = o[d] * sa + o2 * sb;
    }

    if (t < 32) {
        int idx = ((b * Hc + h) * NCH + chunk) * Gc + qidx;
        pm[idx] = M;
        pl[idx] = L;
        #pragma unroll
        for (int d = 0; d < 64; ++d) po[(size_t)idx * 64 + d] = o[d];
    }
}

// ---------------------------------------------------------------------------
// Kernel 4: combine NCH chunk-partials -> out rows [0, G)
// ---------------------------------------------------------------------------
__global__ void global_combine(const float* __restrict__ pm, const float* __restrict__ pl,
                               const float* __restrict__ po, float* __restrict__ out)
{
    const int d = threadIdx.x;
    const int g = blockIdx.x;
    const int h = blockIdx.y;
    const int b = blockIdx.z;
    const int base = ((b * Hc + h) * NCH) * Gc + g;

    float M = -3.0e38f;
    #pragma unroll
    for (int c = 0; c < NCH; ++c) M = fmaxf(M, pm[base + c * Gc]);
    float L = 0.f, O = 0.f;
    #pragma unroll
    for (int c = 0; c < NCH; ++c) {
        float w = __expf(pm[base + c * Gc] - M);
        L = fmaf(pl[base + c * Gc], w, L);
        O = fmaf(po[(size_t)(base + c * Gc) * 64 + d], w, O);
    }
    out[((size_t)b * Sc + g) * Ec + h * HDc + d] = O / L;
}

// ---------------------------------------------------------------------------
extern "C" void kernel_launch(void* const* d_in, const int* in_sizes, int n_in,
                              void* d_out, int out_size, void* d_ws, size_t ws_size,
                              hipStream_t stream)
{
    (void)in_sizes; (void)n_in; (void)out_size;

    const float* hs   = (const float*)d_in[0];
    const float* msk  = (const float*)d_in[1];
    const float* Wq   = (const float*)d_in[2];
    const float* bq   = (const float*)d_in[3];
    const float* Wk   = (const float*)d_in[4];
    const float* bk   = (const float*)d_in[5];
    const float* Wv   = (const float*)d_in[6];
    const float* bv   = (const float*)d_in[7];
    const float* Wqg  = (const float*)d_in[8];
    const float* bqg  = (const float*)d_in[9];
    const float* Wkg  = (const float*)d_in[10];
    const float* bkg  = (const float*)d_in[11];
    const float* Wvg  = (const float*)d_in[12];
    const float* bvg  = (const float*)d_in[13];
    float* out = (float*)d_out;

    const size_t NPROJ = (size_t)Mtot * Ec;     // 6291456
    float* q  = (float*)d_ws;
    float* k  = q  + NPROJ;
    float* v  = k  + NPROJ;
    float* kg = v  + NPROJ;
    float* vg = kg + NPROJ;
    float* qg = vg + NPROJ;                     // 64*768
    float* pm = qg + (size_t)Bc * Gc * Ec;
    float* pl = pm + (size_t)Bc * Hc * NCH * Gc;
    float* po = pl + (size_t)Bc * Hc * NCH * Gc;
    float* fend = po + (size_t)Bc * Hc * NCH * Gc * 64;
    size_t base_bytes = (size_t)((char*)fend - (char*)d_ws);

    ushort* Ah  = (ushort*)fend;
    ushort* Al  = Ah + NPROJ;
    ushort* WTh = Al + NPROJ;                   // 5 x 768*768
    ushort* WTl = WTh + (size_t)5 * Ec * Ec;
    size_t need = base_bytes + (2 * NPROJ + (size_t)10 * Ec * Ec) * 2;
    const bool use_mfma = (ws_size >= need);

    if (use_mfma) {
        split_a<<<dim3(NPROJ / 4 / 256), 256, 0, stream>>>(hs, Ah, Al);
        split_wt<<<dim3(Ec * Ec / 256, 5), 256, 0, stream>>>(Wq, Wk, Wv, Wkg, Wvg, WTh, WTl);
        proj_mfma<<<dim3(Mtot / 128, Ec / 128, 5), 256, 0, stream>>>(
            Ah, Al, WTh, WTl, bq, bk, bv, bkg, bvg, q, k, v, kg, vg);
    } else {
        proj_gemm<<<dim3(Mtot / 128, Ec / 128, 5), 256, 0, stream>>>(
            hs, Wq, bq, q, Wk, bk, k, Wv, bv, v, Wkg, bkg, kg, Wvg, bvg, vg);
    }
    qg_kernel<<<dim3((Bc * Gc * Ec) / 256), 256, 0, stream>>>(hs, Wqg, bqg, qg);
    band_attn<<<dim3(Sc / 128, Hc, Bc), 256, 0, stream>>>(q, k, v, msk, out);
    global_partial<<<dim3(NCH, Hc, Bc), 64, 0, stream>>>(qg, kg, vg, msk, pm, pl, po);
    global_combine<<<dim3(Gc, Hc, Bc), 64, 0, stream>>>(pm, pl, po, out);
}

// Round 7
// 518.588 us; speedup vs baseline: 3.5290x; 2.3015x over previous
//
#include <hip/hip_runtime.h>
#include <hip/hip_bf16.h>

// Problem constants
#define Bc 2
#define Sc 4096
#define Ec 768
#define Hc 12
#define HDc 64
#define Wc 256
#define Gc 32
#define Mtot (Bc*Sc)   // 8192
#define NCH 32         // global-attn key chunks

typedef unsigned short ushort;
typedef __attribute__((ext_vector_type(8))) short short8v;    // 8 bf16 (4 VGPR)
typedef __attribute__((ext_vector_type(4))) float f32x4;      // MFMA acc
typedef __attribute__((ext_vector_type(4))) unsigned short us4v;

__device__ __forceinline__ ushort f2bf(float x) {
    __hip_bfloat16 h = __float2bfloat16(x);
    return *reinterpret_cast<ushort*>(&h);
}
__device__ __forceinline__ float bf2f(ushort u) {
    __hip_bfloat16 h;
    *reinterpret_cast<ushort*>(&h) = u;
    return __bfloat162float(h);
}

__device__ __forceinline__ void gl2lds16(const void* g, void* l) {
    __builtin_amdgcn_global_load_lds(
        (const __attribute__((address_space(1))) void*)g,
        (__attribute__((address_space(3))) void*)l, 16, 0, 0);
}

// ---------------------------------------------------------------------------
// Prep: split fp32 array -> hi, lo (bf16).  Also used for V pre-split.
// ---------------------------------------------------------------------------
__global__ void split_a(const float* __restrict__ x, ushort* __restrict__ hi,
                        ushort* __restrict__ lo)
{
    int id = blockIdx.x * 256 + threadIdx.x;
    float4 v = reinterpret_cast<const float4*>(x)[id];
    float c[4] = {v.x, v.y, v.z, v.w};
    ushort h[4], l[4];
    #pragma unroll
    for (int u = 0; u < 4; ++u) {
        h[u] = f2bf(c[u]);
        l[u] = f2bf(c[u] - bf2f(h[u]));
    }
    us4v hv = {h[0], h[1], h[2], h[3]};
    us4v lv = {l[0], l[1], l[2], l[3]};
    reinterpret_cast<us4v*>(hi)[id] = hv;
    reinterpret_cast<us4v*>(lo)[id] = lv;
}

// ---------------------------------------------------------------------------
// Prep B: per weight z: WTh[n][k] = bf16(W[k][n]), WTl = residual. (transpose)
// ---------------------------------------------------------------------------
__global__ void split_wt(const float* __restrict__ W0, const float* __restrict__ W1,
                         const float* __restrict__ W2, const float* __restrict__ W3,
                         const float* __restrict__ W4,
                         ushort* __restrict__ hi, ushort* __restrict__ lo)
{
    const int z = blockIdx.y;
    const float* W;
    switch (z) {
        case 0: W = W0; break; case 1: W = W1; break; case 2: W = W2; break;
        case 3: W = W3; break; default: W = W4; break;
    }
    int id = blockIdx.x * 256 + threadIdx.x;     // id = n*768 + k
    int n = id / Ec, kk = id - n * Ec;
    float x = W[(size_t)kk * Ec + n];
    ushort h = f2bf(x);
    ushort l = f2bf(x - bf2f(h));
    size_t o = (size_t)z * Ec * Ec + id;
    hi[o] = h;
    lo[o] = l;
}

// ---------------------------------------------------------------------------
// Kernel 1 (MFMA): C_z = hs @ W_z + b_z (q scaled by 0.125), bf16 3-term split.
// ---------------------------------------------------------------------------
__global__ __launch_bounds__(256) void proj_mfma(
    const ushort* __restrict__ Ah, const ushort* __restrict__ Al,
    const ushort* __restrict__ WTh, const ushort* __restrict__ WTl,
    const float* __restrict__ bq,  const float* __restrict__ bk,
    const float* __restrict__ bv,  const float* __restrict__ bkg,
    const float* __restrict__ bvg,
    float* __restrict__ Cq, float* __restrict__ Ck, float* __restrict__ Cv,
    float* __restrict__ Ckg, float* __restrict__ Cvg)
{
    const int z = blockIdx.z;
    const float* bias; float* C; float scale = 1.0f;
    switch (z) {
        case 0:  bias = bq;  C = Cq; scale = 0.125f; break;
        case 1:  bias = bk;  C = Ck;  break;
        case 2:  bias = bv;  C = Cv;  break;
        case 3:  bias = bkg; C = Ckg; break;
        default: bias = bvg; C = Cvg; break;
    }
    const ushort* Bh = WTh + (size_t)z * Ec * Ec;
    const ushort* Bl = WTl + (size_t)z * Ec * Ec;

    __shared__ __align__(16) char smem[32768];

    const int tid = threadIdx.x;
    const int w   = tid >> 6;
    const int lane = tid & 63;
    const int wr  = w >> 1, wc = w & 1;
    const int lr  = lane & 15, kg = lane >> 4;
    const int m0  = blockIdx.x * 128;
    const int n0  = blockIdx.y * 128;

    f32x4 acc[4][4];
    #pragma unroll
    for (int i = 0; i < 4; ++i)
        #pragma unroll
        for (int j = 0; j < 4; ++j) acc[i][j] = (f32x4){0.f, 0.f, 0.f, 0.f};

    for (int k0 = 0; k0 < Ec; k0 += 32) {
        #pragma unroll
        for (int it = 0; it < 4; ++it) {
            int id = it * 256 + tid;
            int r  = id >> 3;
            int ls = (id & 7) ^ (r & 7);
            const ushort* src = (ls < 4)
                ? Ah + ((size_t)(m0 + r) * Ec + k0 + ls * 8)
                : Al + ((size_t)(m0 + r) * Ec + k0 + (ls - 4) * 8);
            gl2lds16(src, smem + id * 16);
        }
        #pragma unroll
        for (int it = 0; it < 4; ++it) {
            int id = it * 256 + tid;
            int r  = id >> 3;
            int ls = (id & 7) ^ (r & 7);
            const ushort* src = (ls < 4)
                ? Bh + ((size_t)(n0 + r) * Ec + k0 + ls * 8)
                : Bl + ((size_t)(n0 + r) * Ec + k0 + (ls - 4) * 8);
            gl2lds16(src, smem + 16384 + id * 16);
        }
        __syncthreads();

        short8v ah[4], al[4], bh[4], bl[4];
        #pragma unroll
        for (int f = 0; f < 4; ++f) {
            int ra = wr * 64 + f * 16 + lr;
            int ba = ra * 128;
            ah[f] = *reinterpret_cast<const short8v*>(smem + ba + ((kg ^ (ra & 7)) << 4));
            al[f] = *reinterpret_cast<const short8v*>(smem + ba + (((kg + 4) ^ (ra & 7)) << 4));
            int rb = wc * 64 + f * 16 + lr;
            int bb = 16384 + rb * 128;
            bh[f] = *reinterpret_cast<const short8v*>(smem + bb + ((kg ^ (rb & 7)) << 4));
            bl[f] = *reinterpret_cast<const short8v*>(smem + bb + (((kg + 4) ^ (rb & 7)) << 4));
        }
        #pragma unroll
        for (int fi = 0; fi < 4; ++fi)
            #pragma unroll
            for (int fj = 0; fj < 4; ++fj) {
                acc[fi][fj] = __builtin_amdgcn_mfma_f32_16x16x32_bf16(ah[fi], bh[fj], acc[fi][fj], 0, 0, 0);
                acc[fi][fj] = __builtin_amdgcn_mfma_f32_16x16x32_bf16(ah[fi], bl[fj], acc[fi][fj], 0, 0, 0);
                acc[fi][fj] = __builtin_amdgcn_mfma_f32_16x16x32_bf16(al[fi], bh[fj], acc[fi][fj], 0, 0, 0);
            }
        __syncthreads();
    }

    #pragma unroll
    for (int fj = 0; fj < 4; ++fj) {
        int col = n0 + wc * 64 + fj * 16 + lr;
        float bsc = bias[col];
        #pragma unroll
        for (int fi = 0; fi < 4; ++fi) {
            int row0 = m0 + wr * 64 + fi * 16 + kg * 4;
            #pragma unroll
            for (int r = 0; r < 4; ++r)
                C[(size_t)(row0 + r) * Ec + col] = (acc[fi][fj][r] + bsc) * scale;
        }
    }
}

// ---------------------------------------------------------------------------
// Kernel 1 fallback (fp32), if workspace too small for bf16 buffers.
// ---------------------------------------------------------------------------
__global__ __launch_bounds__(256) void proj_gemm(
    const float* __restrict__ A,
    const float* __restrict__ Wq,  const float* __restrict__ bq,  float* __restrict__ Cq,
    const float* __restrict__ Wk,  const float* __restrict__ bk,  float* __restrict__ Ck,
    const float* __restrict__ Wv,  const float* __restrict__ bv,  float* __restrict__ Cv,
    const float* __restrict__ Wkg, const float* __restrict__ bkg, float* __restrict__ Ckg,
    const float* __restrict__ Wvg, const float* __restrict__ bvg, float* __restrict__ Cvg)
{
    const int z = blockIdx.z;
    const float* Wm; const float* bias; float* C; float scale = 1.0f;
    switch (z) {
        case 0:  Wm = Wq;  bias = bq;  C = Cq; scale = 0.125f; break;
        case 1:  Wm = Wk;  bias = bk;  C = Ck;  break;
        case 2:  Wm = Wv;  bias = bv;  C = Cv;  break;
        case 3:  Wm = Wkg; bias = bkg; C = Ckg; break;
        default: Wm = Wvg; bias = bvg; C = Cvg; break;
    }
    __shared__ float As[16][132];
    __shared__ float Bs[16][132];
    const int tid = threadIdx.x;
    const int m0 = blockIdx.x * 128;
    const int n0 = blockIdx.y * 128;
    const int tm = (tid >> 4) * 8;
    const int tn = (tid & 15) * 8;
    float acc[8][8];
    #pragma unroll
    for (int i = 0; i < 8; ++i)
        #pragma unroll
        for (int j = 0; j < 8; ++j) acc[i][j] = 0.f;
    for (int k0 = 0; k0 < Ec; k0 += 16) {
        #pragma unroll
        for (int l = 0; l < 2; ++l) {
            int id  = tid + l * 256;
            int row = id >> 2;
            int c4  = (id & 3) * 4;
            float4 av = *reinterpret_cast<const float4*>(&A[(size_t)(m0 + row) * Ec + k0 + c4]);
            As[c4 + 0][row] = av.x; As[c4 + 1][row] = av.y;
            As[c4 + 2][row] = av.z; As[c4 + 3][row] = av.w;
        }
        #pragma unroll
        for (int l = 0; l < 2; ++l) {
            int id  = tid + l * 256;
            int row = id >> 5;
            int c4  = (id & 31) * 4;
            *reinterpret_cast<float4*>(&Bs[row][c4]) =
                *reinterpret_cast<const float4*>(&Wm[(size_t)(k0 + row) * Ec + n0 + c4]);
        }
        __syncthreads();
        #pragma unroll
        for (int kk = 0; kk < 16; ++kk) {
            float a[8], b[8];
            #pragma unroll
            for (int i = 0; i < 8; ++i) a[i] = As[kk][tm + i];
            #pragma unroll
            for (int j = 0; j < 8; ++j) b[j] = Bs[kk][tn + j];
            #pragma unroll
            for (int i = 0; i < 8; ++i)
                #pragma unroll
                for (int j = 0; j < 8; ++j)
                    acc[i][j] = fmaf(a[i], b[j], acc[i][j]);
        }
        __syncthreads();
    }
    #pragma unroll
    for (int i = 0; i < 8; ++i) {
        float r[8];
        #pragma unroll
        for (int j = 0; j < 8; ++j)
            r[j] = (acc[i][j] + bias[n0 + tn + j]) * scale;
        float4 o0 = { r[0], r[1], r[2], r[3] };
        float4 o1 = { r[4], r[5], r[6], r[7] };
        float* cp = &C[(size_t)(m0 + tm + i) * Ec + n0 + tn];
        *reinterpret_cast<float4*>(cp)     = o0;
        *reinterpret_cast<float4*>(cp + 4) = o1;
    }
}

// ---------------------------------------------------------------------------
// Kernel 1b: qg = (hs[:, :G] @ Wqg + bqg) * 0.125
// ---------------------------------------------------------------------------
__global__ void qg_kernel(const float* __restrict__ hs, const float* __restrict__ Wqg,
                          const float* __restrict__ bqg, float* __restrict__ qg)
{
    int idx = blockIdx.x * 256 + threadIdx.x;
    int r = idx / Ec, n = idx - r * Ec;
    int b = r >> 5, g = r & 31;
    const float* a = &hs[(size_t)(b * Sc + g) * Ec];
    float s0 = 0.f, s1 = 0.f, s2 = 0.f, s3 = 0.f;
    for (int k2 = 0; k2 < Ec; k2 += 4) {
        s0 = fmaf(a[k2 + 0], Wqg[(size_t)(k2 + 0) * Ec + n], s0);
        s1 = fmaf(a[k2 + 1], Wqg[(size_t)(k2 + 1) * Ec + n], s1);
        s2 = fmaf(a[k2 + 2], Wqg[(size_t)(k2 + 2) * Ec + n], s2);
        s3 = fmaf(a[k2 + 3], Wqg[(size_t)(k2 + 3) * Ec + n], s3);
    }
    qg[idx] = ((s0 + s1) + (s2 + s3) + bqg[n]) * 0.125f;
}

// ---------------------------------------------------------------------------
// Kernel 2 v4.1 (MFMA): banded sliding-window + global-key attention.
// grid 768 (XCD-swizzled -> (qc 0..31, h, b)), block 256 = 4 waves x 32 q.
// Block stages 21 tiles of 32 keys (global tile + window rel tiles -8..11)
// into LDS (K row-major hi/lo, XOR-swizzled; V packed V^T [d][k] hi/lo).
// Per wave: swapped QK^T (A=K, B=Q) -> S[k][q]; defer-max m=0 softmax;
// P redistributed to A-frag layout via paired shfl + ks-select (fix of R5's
// source-side ks bug); PV via mfma(P, V).  3-term hi/lo bf16 split.
// ---------------------------------------------------------------------------
__global__ __launch_bounds__(256) void band_attn_mfma(
    const float* __restrict__ q, const float* __restrict__ k,
    const ushort* __restrict__ vhi_g, const ushort* __restrict__ vlo_g,
    const float* __restrict__ mask, float* __restrict__ out)
{
    const int bid = blockIdx.x;
    const int swz = (bid & 7) * 96 + (bid >> 3);     // XCD-contiguous (768%8==0)
    const int qc  = swz & 31;
    const int h   = (swz >> 5) % Hc;
    const int b   = swz / (32 * Hc);
    const int tid = threadIdx.x;
    const int w    = tid >> 6;
    const int lane = tid & 63;
    const int lg   = lane >> 4;      // lane group 0..3
    const int lc   = lane & 15;      // lane col 0..15
    const int qb   = qc * 128;
    const int qw   = qb + w * 32;    // wave query base

    __shared__ __align__(16) char lds[16512];
    const int KHI = 0, KLO = 4096, VHI = 8192, VLO = 12288, FMO = 16384;

    const size_t hbase = (size_t)h * HDc;

    // Q fragments (hi/lo): [qsub][dhalf], lane holds Q[q=lc][d=dh*32+lg*8 ..+8]
    short8v qh[2][2], qlv[2][2];
    #pragma unroll
    for (int qs = 0; qs < 2; ++qs)
        #pragma unroll
        for (int dh = 0; dh < 2; ++dh) {
            int row = qw + qs * 16 + lc;
            const float* qp = q + ((size_t)(b * Sc + row)) * Ec + hbase + dh * 32 + lg * 8;
            float4 f0 = *reinterpret_cast<const float4*>(qp);
            float4 f1 = *reinterpret_cast<const float4*>(qp + 4);
            float vals[8] = {f0.x, f0.y, f0.z, f0.w, f1.x, f1.y, f1.z, f1.w};
            short8v hh, llv;
            #pragma unroll
            for (int jx = 0; jx < 8; ++jx) {
                ushort hb = f2bf(vals[jx]);
                hh[jx]  = (short)hb;
                llv[jx] = (short)f2bf(vals[jx] - bf2f(hb));
            }
            qh[qs][dh] = hh; qlv[qs][dh] = llv;
        }

    f32x4 acc[2][4];
    #pragma unroll
    for (int qs = 0; qs < 2; ++qs)
        #pragma unroll
        for (int ds = 0; ds < 4; ++ds) acc[qs][ds] = (f32x4){0.f, 0.f, 0.f, 0.f};
    float l_acc[2] = {0.f, 0.f};

    for (int st = 0; st < 21; ++st) {
        const bool is_g = (st == 0);
        const int  t    = st - 9;                 // window rel tile -8..11
        const int  j0   = is_g ? 0 : (qb + t * 32);
        if (!is_g && (j0 + 31 < 0 || j0 >= Sc)) continue;   // block-uniform

        __syncthreads();
        // ---- stage K (hi/lo, XOR-swizzled row-major [32k][64d]) ----
        #pragma unroll
        for (int it = 0; it < 2; ++it) {
            int id  = it * 256 + tid;     // 0..511
            int row = id >> 4;            // 0..31
            int d0  = (id & 15) * 4;
            int j   = j0 + row;
            float4 kf = {0.f, 0.f, 0.f, 0.f};
            if (j >= 0 && j < Sc)
                kf = *reinterpret_cast<const float4*>(&k[((size_t)(b * Sc + j)) * Ec + hbase + d0]);
            float kv[4] = {kf.x, kf.y, kf.z, kf.w};
            us4v h4, l4;
            #pragma unroll
            for (int i2 = 0; i2 < 4; ++i2) {
                ushort hb = f2bf(kv[i2]);
                h4[i2] = hb;
                l4[i2] = f2bf(kv[i2] - bf2f(hb));
            }
            int ab = row * 128 + (((d0 >> 3) ^ (row & 7)) << 4) + ((d0 & 4) << 1);
            *reinterpret_cast<us4v*>(lds + KHI + ab) = h4;
            *reinterpret_cast<us4v*>(lds + KLO + ab) = l4;
        }
        // ---- stage V (V^T [d][32k] shorts, hi/lo) ----
        #pragma unroll
        for (int it = 0; it < 2; ++it) {
            int id  = it * 256 + tid;
            int row = id & 31;
            int d0  = (id >> 5) * 4;      // 0..60
            int j   = j0 + row;
            us4v h4 = {0, 0, 0, 0}, l4 = {0, 0, 0, 0};
            if (j >= 0 && j < Sc) {
                size_t o = ((size_t)(b * Sc + j)) * Ec + hbase + d0;
                h4 = *reinterpret_cast<const us4v*>(&vhi_g[o]);
                l4 = *reinterpret_cast<const us4v*>(&vlo_g[o]);
            }
            int kgrp = row >> 3, kkk = row & 7;
            #pragma unroll
            for (int i2 = 0; i2 < 4; ++i2) {
                int idx = (((d0 + i2) << 2) + kgrp) * 8 + kkk;
                *reinterpret_cast<ushort*>(lds + VHI + idx * 2) = h4[i2];
                *reinterpret_cast<ushort*>(lds + VLO + idx * 2) = l4[i2];
            }
        }
        if (tid < 32) {
            int j = j0 + tid;
            float f = 0.f;
            if (!is_g) {
                if (j < 0 || j >= Sc) f = -1.0e9f;
                else if (mask[b * Sc + j] != 0.f) f = -10000.f;
            }
            *reinterpret_cast<float*>(lds + FMO + tid * 4) = f;
        }
        __syncthreads();

        const bool active = is_g || (t >= w - 8 && t <= w + 8);
        if (!active) continue;

        // ---- K fragments ----
        short8v kh[2][2], klv[2][2];      // [ksub][dhalf]
        #pragma unroll
        for (int ks = 0; ks < 2; ++ks)
            #pragma unroll
            for (int dh = 0; dh < 2; ++dh) {
                int krow = ks * 16 + lc;
                int ab = krow * 128 + ((((dh << 2) + lg) ^ (krow & 7)) << 4);
                kh[ks][dh]  = *reinterpret_cast<const short8v*>(lds + KHI + ab);
                klv[ks][dh] = *reinterpret_cast<const short8v*>(lds + KLO + ab);
            }

        // ---- QK^T: S[k][q] ----
        f32x4 S[2][2];                    // [ksub][qsub]
        #pragma unroll
        for (int ks = 0; ks < 2; ++ks)
            #pragma unroll
            for (int qs = 0; qs < 2; ++qs) {
                f32x4 s = (f32x4){0.f, 0.f, 0.f, 0.f};
                #pragma unroll
                for (int dh = 0; dh < 2; ++dh) {
                    s = __builtin_amdgcn_mfma_f32_16x16x32_bf16(kh[ks][dh],  qh[qs][dh],  s, 0, 0, 0);
                    s = __builtin_amdgcn_mfma_f32_16x16x32_bf16(kh[ks][dh],  qlv[qs][dh], s, 0, 0, 0);
                    s = __builtin_amdgcn_mfma_f32_16x16x32_bf16(klv[ks][dh], qh[qs][dh],  s, 0, 0, 0);
                }
                S[ks][qs] = s;
            }

        f32x4 fm4[2];
        #pragma unroll
        for (int ks = 0; ks < 2; ++ks)
            fm4[ks] = *reinterpret_cast<const f32x4*>(lds + FMO + (ks * 16 + lg * 4) * 4);

        // ---- mask + exp (defer-max, m == 0) ----
        float p[2][2][4];
        #pragma unroll
        for (int ks = 0; ks < 2; ++ks)
            #pragma unroll
            for (int qs = 0; qs < 2; ++qs) {
                int qa = qw + qs * 16 + lc;
                #pragma unroll
                for (int r = 0; r < 4; ++r) {
                    float s = S[ks][qs][r];
                    if (!is_g) {
                        s += fm4[ks][r];
                        int jj = j0 + ks * 16 + lg * 4 + r;
                        if ((unsigned)(jj - qa + Wc) > 2u * Wc) s = -1.0e9f;
                    }
                    float pv = __expf(s);
                    l_acc[qs] += pv;
                    p[ks][qs][r] = pv;
                }
            }

        // ---- redistribute P to A-frag layout (paired shfl + ks select) ----
        // dest lane (lg,lc), elem j: key = lg*8+j -> ks_src = lg>>1,
        // src lane = ((lg&1)*2 + (j>>2))*16 + lc, r = j&3.
        short8v pah[2], pal[2];
        const int src0 = ((lg & 1) << 5) + lc;
        const bool hi_ks = (lg >= 2);
        #pragma unroll
        for (int qs = 0; qs < 2; ++qs) {
            float pj[8];
            #pragma unroll
            for (int jx = 0; jx < 4; ++jx) {
                float t0 = __shfl(p[0][qs][jx], src0);
                float t1 = __shfl(p[1][qs][jx], src0);
                pj[jx] = hi_ks ? t1 : t0;
                float u0 = __shfl(p[0][qs][jx], src0 + 16);
                float u1 = __shfl(p[1][qs][jx], src0 + 16);
                pj[jx + 4] = hi_ks ? u1 : u0;
            }
            short8v hh, llv;
            #pragma unroll
            for (int jx = 0; jx < 8; ++jx) {
                ushort hb = f2bf(pj[jx]);
                hh[jx]  = (short)hb;
                llv[jx] = (short)f2bf(pj[jx] - bf2f(hb));
            }
            pah[qs] = hh; pal[qs] = llv;
        }

        // ---- PV: O[q][d] += P V ----
        #pragma unroll
        for (int ds = 0; ds < 4; ++ds) {
            int vb = (((ds * 16 + lc) << 2) + lg) << 4;
            short8v vh = *reinterpret_cast<const short8v*>(lds + VHI + vb);
            short8v vl = *reinterpret_cast<const short8v*>(lds + VLO + vb);
            #pragma unroll
            for (int qs = 0; qs < 2; ++qs) {
                acc[qs][ds] = __builtin_amdgcn_mfma_f32_16x16x32_bf16(pah[qs], vh, acc[qs][ds], 0, 0, 0);
                acc[qs][ds] = __builtin_amdgcn_mfma_f32_16x16x32_bf16(pah[qs], vl, acc[qs][ds], 0, 0, 0);
                acc[qs][ds] = __builtin_amdgcn_mfma_f32_16x16x32_bf16(pal[qs], vh, acc[qs][ds], 0, 0, 0);
            }
        }
    }

    // ---- epilogue: reduce l across k-groups, normalize, write ----
    float linv[2];
    #pragma unroll
    for (int qs = 0; qs < 2; ++qs) {
        float lv = l_acc[qs];
        lv += __shfl_xor(lv, 16);
        lv += __shfl_xor(lv, 32);
        linv[qs] = 1.0f / lv;
    }
    #pragma unroll
    for (int qs = 0; qs < 2; ++qs) {
        float rv[4];
        #pragma unroll
        for (int r = 0; r < 4; ++r)
            rv[r] = __shfl(linv[qs], lg * 4 + r);
        #pragma unroll
        for (int ds = 0; ds < 4; ++ds) {
            #pragma unroll
            for (int r = 0; r < 4; ++r) {
                int row = qw + qs * 16 + lg * 4 + r;
                out[((size_t)(b * Sc + row)) * Ec + hbase + ds * 16 + lc] = acc[qs][ds][r] * rv[r];
            }
        }
    }
}

// ---------------------------------------------------------------------------
// Kernel 3: global-row attention, partials over NCH chunks of S/NCH keys.
// ---------------------------------------------------------------------------
__global__ __launch_bounds__(64, 2) void global_partial(
    const float* __restrict__ qg, const float* __restrict__ kg, const float* __restrict__ vg,
    const float* __restrict__ mask,
    float* __restrict__ pm, float* __restrict__ pl, float* __restrict__ po)
{
    const int t     = threadIdx.x;
    const int qidx  = t & 31;
    const int half  = t >> 5;
    const int chunk = blockIdx.x;
    const int h     = blockIdx.y;
    const int b     = blockIdx.z;

    __shared__ float ks[64][64];
    __shared__ float vs[64][64];
    __shared__ float fl[64];

    const size_t kbase = ((size_t)b * Sc) * Ec + (size_t)h * HDc;

    float qr[64];
    {
        const float* qp = &qg[(size_t)(b * Gc + qidx) * Ec + h * HDc];
        #pragma unroll
        for (int c = 0; c < 16; ++c) {
            float4 t4 = *reinterpret_cast<const float4*>(&qp[c * 4]);
            qr[c*4+0] = t4.x; qr[c*4+1] = t4.y; qr[c*4+2] = t4.z; qr[c*4+3] = t4.w;
        }
    }

    float m = 0.f, l = 0.f;
    float o[64];
    #pragma unroll
    for (int d = 0; d < 64; ++d) o[d] = 0.f;

    const int c0 = chunk * (Sc / NCH);
    for (int tt = 0; tt < (Sc / NCH) / 64; ++tt) {
        const int j0 = c0 + tt * 64;
        __syncthreads();
        #pragma unroll
        for (int r4 = 0; r4 < 16; ++r4) {
            int id  = r4 * 64 + t;
            int row = id >> 4;
            int c4  = (id & 15) * 4;
            int j   = j0 + row;
            *reinterpret_cast<float4*>(&ks[row][c4]) =
                *reinterpret_cast<const float4*>(&kg[kbase + (size_t)j * Ec + c4]);
            *reinterpret_cast<float4*>(&vs[row][c4]) =
                *reinterpret_cast<const float4*>(&vg[kbase + (size_t)j * Ec + c4]);
        }
        {
            int j = j0 + t;
            fl[t] = (mask[b * Sc + j] < 0.f) ? 1.f : 0.f;
        }
        __syncthreads();

        for (int jj2 = 0; jj2 < 32; ++jj2) {
            int jj = half + 2 * jj2;
            const float4* kp4 = reinterpret_cast<const float4*>(&ks[jj][0]);
            float4 a4 = {0.f, 0.f, 0.f, 0.f};
            #pragma unroll
            for (int c = 0; c < 16; ++c) {
                float4 kv = kp4[c];
                a4.x = fmaf(qr[c*4+0], kv.x, a4.x);
                a4.y = fmaf(qr[c*4+1], kv.y, a4.y);
                a4.z = fmaf(qr[c*4+2], kv.z, a4.z);
                a4.w = fmaf(qr[c*4+3], kv.w, a4.w);
            }
            float s = (a4.x + a4.y) + (a4.z + a4.w);
            if (fl[jj] != 0.f) s = -10000.f;
            if (__any(s > m + 8.0f)) {
                float nm = fmaxf(m, s);
                float cc = __expf(m - nm);
                l *= cc;
                #pragma unroll
                for (int d = 0; d < 64; ++d) o[d] *= cc;
                m = nm;
            }
            float pv = __expf(s - m);
            l += pv;
            const float4* vp4 = reinterpret_cast<const float4*>(&vs[jj][0]);
            #pragma unroll
            for (int c = 0; c < 16; ++c) {
                float4 vv = vp4[c];
                o[c*4+0] = fmaf(pv, vv.x, o[c*4+0]);
                o[c*4+1] = fmaf(pv, vv.y, o[c*4+1]);
                o[c*4+2] = fmaf(pv, vv.z, o[c*4+2]);
                o[c*4+3] = fmaf(pv, vv.w, o[c*4+3]);
            }
        }
    }

    float m2 = __shfl_xor(m, 32);
    float M  = fmaxf(m, m2);
    float sa = __expf(m - M);
    float sb = __expf(m2 - M);
    float l2 = __shfl_xor(l, 32);
    float L  = l * sa + l2 * sb;
    #pragma unroll
    for (int d = 0; d < 64; ++d) {
        float o2 = __shfl_xor(o[d], 32);
        o[d] = o[d] * sa + o2 * sb;
    }

    if (t < 32) {
        int idx = ((b * Hc + h) * NCH + chunk) * Gc + qidx;
        pm[idx] = M;
        pl[idx] = L;
        #pragma unroll
        for (int d = 0; d < 64; ++d) po[(size_t)idx * 64 + d] = o[d];
    }
}

// ---------------------------------------------------------------------------
// Kernel 4: combine NCH chunk-partials -> out rows [0, G)
// ---------------------------------------------------------------------------
__global__ void global_combine(const float* __restrict__ pm, const float* __restrict__ pl,
                               const float* __restrict__ po, float* __restrict__ out)
{
    const int d = threadIdx.x;
    const int g = blockIdx.x;
    const int h = blockIdx.y;
    const int b = blockIdx.z;
    const int base = ((b * Hc + h) * NCH) * Gc + g;

    float M = -3.0e38f;
    #pragma unroll
    for (int c = 0; c < NCH; ++c) M = fmaxf(M, pm[base + c * Gc]);
    float L = 0.f, O = 0.f;
    #pragma unroll
    for (int c = 0; c < NCH; ++c) {
        float w = __expf(pm[base + c * Gc] - M);
        L = fmaf(pl[base + c * Gc], w, L);
        O = fmaf(po[(size_t)(base + c * Gc) * 64 + d], w, O);
    }
    out[((size_t)b * Sc + g) * Ec + h * HDc + d] = O / L;
}

// ---------------------------------------------------------------------------
extern "C" void kernel_launch(void* const* d_in, const int* in_sizes, int n_in,
                              void* d_out, int out_size, void* d_ws, size_t ws_size,
                              hipStream_t stream)
{
    (void)in_sizes; (void)n_in; (void)out_size;

    const float* hs   = (const float*)d_in[0];
    const float* msk  = (const float*)d_in[1];
    const float* Wq   = (const float*)d_in[2];
    const float* bq   = (const float*)d_in[3];
    const float* Wk   = (const float*)d_in[4];
    const float* bk   = (const float*)d_in[5];
    const float* Wv   = (const float*)d_in[6];
    const float* bv   = (const float*)d_in[7];
    const float* Wqg  = (const float*)d_in[8];
    const float* bqg  = (const float*)d_in[9];
    const float* Wkg  = (const float*)d_in[10];
    const float* bkg  = (const float*)d_in[11];
    const float* Wvg  = (const float*)d_in[12];
    const float* bvg  = (const float*)d_in[13];
    float* out = (float*)d_out;

    const size_t NPROJ = (size_t)Mtot * Ec;     // 6291456
    float* q  = (float*)d_ws;
    float* k  = q  + NPROJ;
    float* v  = k  + NPROJ;
    float* kg = v  + NPROJ;
    float* vg = kg + NPROJ;
    float* qg = vg + NPROJ;
    float* pm = qg + (size_t)Bc * Gc * Ec;
    float* pl = pm + (size_t)Bc * Hc * NCH * Gc;
    float* po = pl + (size_t)Bc * Hc * NCH * Gc;
    float* fend = po + (size_t)Bc * Hc * NCH * Gc * 64;
    size_t base_bytes = (size_t)((char*)fend - (char*)d_ws);

    ushort* Ah  = (ushort*)fend;               // later reused as vhi
    ushort* Al  = Ah + NPROJ;                  // later reused as vlo
    ushort* WTh = Al + NPROJ;
    ushort* WTl = WTh + (size_t)5 * Ec * Ec;
    size_t need = base_bytes + (2 * NPROJ + (size_t)10 * Ec * Ec) * 2;
    const bool use_mfma = (ws_size >= need);

    if (use_mfma) {
        split_a<<<dim3(NPROJ / 4 / 256), 256, 0, stream>>>(hs, Ah, Al);
        split_wt<<<dim3(Ec * Ec / 256, 5), 256, 0, stream>>>(Wq, Wk, Wv, Wkg, Wvg, WTh, WTl);
        proj_mfma<<<dim3(Mtot / 128, Ec / 128, 5), 256, 0, stream>>>(
            Ah, Al, WTh, WTl, bq, bk, bv, bkg, bvg, q, k, v, kg, vg);
    } else {
        proj_gemm<<<dim3(Mtot / 128, Ec / 128, 5), 256, 0, stream>>>(
            hs, Wq, bq, q, Wk, bk, k, Wv, bv, v, Wkg, bkg, kg, Wvg, bvg, vg);
    }
    qg_kernel<<<dim3((Bc * Gc * Ec) / 256), 256, 0, stream>>>(hs, Wqg, bqg, qg);
    // re-split V into bf16 hi/lo, reusing the Ah/Al region (proj done with it)
    split_a<<<dim3(NPROJ / 4 / 256), 256, 0, stream>>>(v, Ah, Al);
    band_attn_mfma<<<dim3(32 * Hc * Bc), 256, 0, stream>>>(q, k, Ah, Al, msk, out);
    global_partial<<<dim3(NCH, Hc, Bc), 64, 0, stream>>>(qg, kg, vg, msk, pm, pl, po);
    global_combine<<<dim3(Gc, Hc, Bc), 64, 0, stream>>>(pm, pl, po, out);
}